// Round 1
// baseline (2667.952 us; speedup 1.0000x reference)
//
#include <hip/hip_runtime.h>
#include <math.h>

// ============================================================================
// MixtralDecoderLayer on MI355X — Round 0: correctness-first fp32 baseline.
//
//   B=1 S=2048 H=1024 NH=16 NKV=4 HD=64 I=3584 E=8 TOPK=2
//
// Pipeline (all on `stream`):
//   1) zero routing counters
//   2) rmsnorm(hidden, input_norm_w)            -> xn
//   3) xn @ wq -> q ; xn @ wk -> k ; xn @ wv -> v
//   4) rope(q, k) in place
//   5) flash attention (causal, GQA)            -> attn
//   6) attn @ wo + hidden                       -> d_out   (this is "h")
//   7) rmsnorm(d_out, post_norm_w)              -> xn
//   8) gate: logits, top-2, counts
//   9) prefix-sum counts -> per-expert offsets
//  10) fill compacted (token, weight) lists
//  11) grouped GEMM1: silu(x@w1[e]) * (x@w3[e]) -> hexp (4096 rows)
//  12) grouped GEMM2: hexp @ w2[e] * wt -> atomicAdd into d_out
//
// ws layout (fp32 elements):
//   [0, 2M)                  xn
//   [2M, 2M+16448)           routing: cnt[8] offs[9] cur[8] top_i[4096]
//                            idxg[4096] top_w[4096] wtg[4096]
//   [BIG, BIG+14.68M)        q(2M) k(0.5M) v(0.5M) attn(2M)  -- later reused
//                            as hexp[4096][3584]
//   total ~64.1 MB
// ============================================================================

#define S_LEN 2048
#define HDIM  1024
#define NHEAD 16
#define NKVH  4
#define HD    64
#define ISZ   3584
#define NEXP  8
#define EPS_F 1e-5f
#define NEG_INF -1e30f

// ---------------------------------------------------------------------------
__global__ void k_zero_ints(int* __restrict__ p, int n) {
    int i = blockIdx.x * blockDim.x + threadIdx.x;
    if (i < n) p[i] = 0;
}

// ---------------------------------------------------------------------------
// RMSNorm: one block per token, 256 threads, 4 floats/thread (H=1024).
__global__ __launch_bounds__(256)
void k_rmsnorm(const float* __restrict__ x, const float* __restrict__ w,
               float* __restrict__ out) {
    int t = blockIdx.x;
    int tid = threadIdx.x;
    float4 v = ((const float4*)(x + (size_t)t * HDIM))[tid];
    float ss = v.x * v.x + v.y * v.y + v.z * v.z + v.w * v.w;
#pragma unroll
    for (int off = 32; off >= 1; off >>= 1) ss += __shfl_xor(ss, off, 64);
    __shared__ float red[4];
    if ((tid & 63) == 0) red[tid >> 6] = ss;
    __syncthreads();
    float tot = red[0] + red[1] + red[2] + red[3];
    float rstd = rsqrtf(tot * (1.0f / HDIM) + EPS_F);
    float4 wv = ((const float4*)w)[tid];
    float4 o;
    o.x = v.x * rstd * wv.x; o.y = v.y * rstd * wv.y;
    o.z = v.z * rstd * wv.z; o.w = v.w * rstd * wv.w;
    ((float4*)(out + (size_t)t * HDIM))[tid] = o;
}

// ---------------------------------------------------------------------------
// Plain fp32 GEMM: C[M,N] = A[M,K] @ B[K,N] (+ RES). 64x64 tile, BK=16,
// 256 threads, 4x4 outputs/thread. M,N multiples of 64; K multiple of 16.
__global__ __launch_bounds__(256)
void k_gemm(const float* __restrict__ A, const float* __restrict__ B,
            const float* __restrict__ RES, float* __restrict__ C,
            int M, int N, int K) {
    __shared__ float As[16][64];   // transposed A tile: As[k][m]
    __shared__ float Bs[16][64];
    const int tid = threadIdx.x;
    const int row0 = blockIdx.y * 64, col0 = blockIdx.x * 64;
    const int ty = tid >> 4, tx = tid & 15;
    const int arow = tid >> 2, acol = (tid & 3) << 2;
    const int brow = tid >> 4, bcol = (tid & 15) << 2;
    const float* Ap = A + (size_t)(row0 + arow) * K + acol;
    const float* Bp = B + (size_t)brow * N + col0 + bcol;
    float acc[4][4] = {};
    for (int k0 = 0; k0 < K; k0 += 16) {
        float4 av = *(const float4*)(Ap + k0);
        float4 bv = *(const float4*)(Bp + (size_t)k0 * N);
        __syncthreads();
        As[acol + 0][arow] = av.x; As[acol + 1][arow] = av.y;
        As[acol + 2][arow] = av.z; As[acol + 3][arow] = av.w;
        *(float4*)&Bs[brow][bcol] = bv;
        __syncthreads();
#pragma unroll
        for (int kk = 0; kk < 16; kk++) {
            float4 a4 = *(const float4*)&As[kk][ty << 2];
            float4 b4 = *(const float4*)&Bs[kk][tx << 2];
            float a_[4] = {a4.x, a4.y, a4.z, a4.w};
            float b_[4] = {b4.x, b4.y, b4.z, b4.w};
#pragma unroll
            for (int i = 0; i < 4; i++)
#pragma unroll
                for (int j = 0; j < 4; j++)
                    acc[i][j] = fmaf(a_[i], b_[j], acc[i][j]);
        }
    }
#pragma unroll
    for (int i = 0; i < 4; i++) {
        size_t off = (size_t)(row0 + (ty << 2) + i) * N + col0 + (tx << 2);
        float4 r;
        r.x = acc[i][0]; r.y = acc[i][1]; r.z = acc[i][2]; r.w = acc[i][3];
        if (RES != nullptr) {
            float4 rv = *(const float4*)(RES + off);
            r.x += rv.x; r.y += rv.y; r.z += rv.z; r.w += rv.w;
        }
        *(float4*)(C + off) = r;
    }
}

// ---------------------------------------------------------------------------
// RoPE in place on q [S][NH*HD] and k [S][NKV*HD].
// Thread -> (s, head-slot hh in [0,20), d in [0,32)); handles d and d+32.
__global__ __launch_bounds__(256)
void k_rope(float* __restrict__ q, float* __restrict__ k,
            const int* __restrict__ pos) {
    int id = blockIdx.x * blockDim.x + threadIdx.x;
    int d = id & 31;
    int hh = (id >> 5) % (NHEAD + NKVH);
    int s = id / ((NHEAD + NKVH) * 32);
    float p = (float)pos[s];
    // inv_freq = THETA^(-2d/HD)
    float inv = exp2f(-((float)(2 * d) / (float)HD) * log2f(1.0e6f));
    float ang = p * inv;
    float c = cosf(ang), sn = sinf(ang);
    float* ptr = (hh < NHEAD)
                     ? (q + (size_t)s * (NHEAD * HD) + hh * HD)
                     : (k + (size_t)s * (NKVH * HD) + (hh - NHEAD) * HD);
    float x1 = ptr[d], x2 = ptr[d + 32];
    ptr[d]      = x1 * c - x2 * sn;
    ptr[d + 32] = x2 * c + x1 * sn;
}

// ---------------------------------------------------------------------------
// Flash attention, causal, GQA (head h uses kv head h>>2).
// Block = (qtile of 64 queries, head). 256 threads.
// Thread (rgrp=tid>>4, cgrp=tid&15): score rows r=rgrp*4+i, cols c=cgrp+16j;
// output dims d=cgrp*4+jd. LDS tiles [64][64] with rotation swizzle
// phys_col = (col + 4*row) & 63 -> all accesses <=2-way bank aliasing.
__device__ __forceinline__ float4 ld4sw(const float* t, int r, int c4) {
    return *(const float4*)&t[r * 64 + (((c4 + r) & 15) << 2)];
}
__device__ __forceinline__ void st4sw(float* t, int r, int c4, float4 v) {
    *(float4*)&t[r * 64 + (((c4 + r) & 15) << 2)] = v;
}

__global__ __launch_bounds__(256)
void k_attn(const float* __restrict__ q, const float* __restrict__ kb,
            const float* __restrict__ vb, float* __restrict__ ob) {
    __shared__ float Qt[64 * 64];
    __shared__ float Kt[64 * 64];
    __shared__ float Vt[64 * 64];
    __shared__ float Pst[64 * 64];
    const int qt = blockIdx.x, h = blockIdx.y;
    const int kvh = h >> 2;
    const int tid = threadIdx.x;
    const int rgrp = tid >> 4, cgrp = tid & 15;
    const int lrow = tid >> 4, ld4 = tid & 15;

#pragma unroll
    for (int rr = 0; rr < 4; rr++) {
        int r = lrow + rr * 16;
        float4 val = *(const float4*)(q + (size_t)(qt * 64 + r) * HDIM +
                                      h * HD + ld4 * 4);
        st4sw(Qt, r, ld4, val);
    }
    float mI[4], lI[4], O[4][4];
#pragma unroll
    for (int i = 0; i < 4; i++) {
        mI[i] = NEG_INF; lI[i] = 0.0f;
#pragma unroll
        for (int j = 0; j < 4; j++) O[i][j] = 0.0f;
    }

    for (int kt = 0; kt <= qt; kt++) {
        __syncthreads();   // previous tile's Kt/Vt/Pst fully consumed
#pragma unroll
        for (int rr = 0; rr < 4; rr++) {
            int r = lrow + rr * 16;
            size_t gro = (size_t)(kt * 64 + r) * (NKVH * HD) + kvh * HD + ld4 * 4;
            st4sw(Kt, r, ld4, *(const float4*)(kb + gro));
            st4sw(Vt, r, ld4, *(const float4*)(vb + gro));
        }
        __syncthreads();

        float s[4][4] = {};
#pragma unroll
        for (int d4 = 0; d4 < 16; d4++) {
            float4 qv[4];
#pragma unroll
            for (int i = 0; i < 4; i++) qv[i] = ld4sw(Qt, rgrp * 4 + i, d4);
#pragma unroll
            for (int j = 0; j < 4; j++) {
                float4 kv = ld4sw(Kt, cgrp + 16 * j, d4);
#pragma unroll
                for (int i = 0; i < 4; i++) {
                    s[i][j] = fmaf(qv[i].x, kv.x, s[i][j]);
                    s[i][j] = fmaf(qv[i].y, kv.y, s[i][j]);
                    s[i][j] = fmaf(qv[i].z, kv.z, s[i][j]);
                    s[i][j] = fmaf(qv[i].w, kv.w, s[i][j]);
                }
            }
        }
        const bool diag = (kt == qt);
        float mt[4];
#pragma unroll
        for (int i = 0; i < 4; i++) {
#pragma unroll
            for (int j = 0; j < 4; j++) {
                s[i][j] *= 0.125f;   // HD^-0.5
                if (diag && (cgrp + 16 * j) > (rgrp * 4 + i)) s[i][j] = NEG_INF;
            }
            mt[i] = fmaxf(fmaxf(s[i][0], s[i][1]), fmaxf(s[i][2], s[i][3]));
        }
#pragma unroll
        for (int off = 8; off >= 1; off >>= 1)
#pragma unroll
            for (int i = 0; i < 4; i++)
                mt[i] = fmaxf(mt[i], __shfl_xor(mt[i], off, 64));

        float rs[4];
#pragma unroll
        for (int i = 0; i < 4; i++) {
            float mn = fmaxf(mI[i], mt[i]);
            float alpha = expf(mI[i] - mn);
            mI[i] = mn;
            float r0 = 0.0f;
#pragma unroll
            for (int j = 0; j < 4; j++) {
                s[i][j] = expf(s[i][j] - mn);   // now holds p
                r0 += s[i][j];
            }
            rs[i] = r0;
            lI[i] *= alpha;
#pragma unroll
            for (int jd = 0; jd < 4; jd++) O[i][jd] *= alpha;
        }
#pragma unroll
        for (int off = 8; off >= 1; off >>= 1)
#pragma unroll
            for (int i = 0; i < 4; i++) rs[i] += __shfl_xor(rs[i], off, 64);
#pragma unroll
        for (int i = 0; i < 4; i++) lI[i] += rs[i];

        // stage P
#pragma unroll
        for (int i = 0; i < 4; i++) {
            int r = rgrp * 4 + i;
#pragma unroll
            for (int j = 0; j < 4; j++) {
                int c = cgrp + 16 * j;
                Pst[r * 64 + ((c + 4 * r) & 63)] = s[i][j];
            }
        }
        __syncthreads();

        // O += P @ V
#pragma unroll
        for (int c4 = 0; c4 < 16; c4++) {
            float pv[4][4];
#pragma unroll
            for (int i = 0; i < 4; i++) {
                float4 p4 = ld4sw(Pst, rgrp * 4 + i, c4);
                pv[i][0] = p4.x; pv[i][1] = p4.y; pv[i][2] = p4.z; pv[i][3] = p4.w;
            }
#pragma unroll
            for (int cc = 0; cc < 4; cc++) {
                int c = c4 * 4 + cc;
                float4 vv = ld4sw(Vt, c, cgrp);
                float v_[4] = {vv.x, vv.y, vv.z, vv.w};
#pragma unroll
                for (int i = 0; i < 4; i++)
#pragma unroll
                    for (int jd = 0; jd < 4; jd++)
                        O[i][jd] = fmaf(pv[i][cc], v_[jd], O[i][jd]);
            }
        }
    }

#pragma unroll
    for (int i = 0; i < 4; i++) {
        float inv = 1.0f / lI[i];
        int gq = qt * 64 + rgrp * 4 + i;
        float4 res;
        res.x = O[i][0] * inv; res.y = O[i][1] * inv;
        res.z = O[i][2] * inv; res.w = O[i][3] * inv;
        *(float4*)(ob + (size_t)gq * HDIM + h * HD + cgrp * 4) = res;
    }
}

// ---------------------------------------------------------------------------
// Router gate: one wave per token. logits = xn @ gate_w [H,8]; top-2 of
// softmax renormalized == sigmoid of logit gap.
__global__ __launch_bounds__(64)
void k_gate(const float* __restrict__ X, const float* __restrict__ GW,
            int* __restrict__ cnt, int* __restrict__ top_i,
            float* __restrict__ top_w) {
    int t = blockIdx.x;
    int lane = threadIdx.x;
    float acc[NEXP] = {};
    for (int hh = lane; hh < HDIM; hh += 64) {
        float xv = X[(size_t)t * HDIM + hh];
        const float* g = GW + (size_t)hh * NEXP;
#pragma unroll
        for (int e = 0; e < NEXP; e++) acc[e] += xv * g[e];
    }
#pragma unroll
    for (int e = 0; e < NEXP; e++)
#pragma unroll
        for (int off = 32; off >= 1; off >>= 1)
            acc[e] += __shfl_xor(acc[e], off, 64);
    if (lane == 0) {
        int e0 = 0;
        for (int e = 1; e < NEXP; e++) if (acc[e] > acc[e0]) e0 = e;
        int e1 = (e0 == 0) ? 1 : 0;
        for (int e = 0; e < NEXP; e++)
            if (e != e0 && acc[e] > acc[e1]) e1 = e;
        float w0 = 1.0f / (1.0f + expf(acc[e1] - acc[e0]));
        top_i[t * 2 + 0] = e0; top_i[t * 2 + 1] = e1;
        top_w[t * 2 + 0] = w0; top_w[t * 2 + 1] = 1.0f - w0;
        atomicAdd(&cnt[e0], 1);
        atomicAdd(&cnt[e1], 1);
    }
}

__global__ void k_prefix(const int* __restrict__ cnt, int* __restrict__ offs,
                         int* __restrict__ cur) {
    if (blockIdx.x == 0 && threadIdx.x == 0) {
        int a = 0;
        for (int e = 0; e < NEXP; e++) { offs[e] = a; cur[e] = a; a += cnt[e]; }
        offs[NEXP] = a;   // == 4096
    }
}

__global__ __launch_bounds__(256)
void k_fill(const int* __restrict__ top_i, const float* __restrict__ top_w,
            int* __restrict__ cur, int* __restrict__ idxg,
            float* __restrict__ wtg) {
    int t = blockIdx.x * blockDim.x + threadIdx.x;
    if (t >= S_LEN) return;
#pragma unroll
    for (int kk = 0; kk < 2; kk++) {
        int e = top_i[t * 2 + kk];
        int p = atomicAdd(&cur[e], 1);
        idxg[p] = t;
        wtg[p] = top_w[t * 2 + kk];
    }
}

// ---------------------------------------------------------------------------
// Grouped MoE GEMM1: hexp[row] = silu(x@w1[e]) * (x@w3[e]) for routed rows.
__global__ __launch_bounds__(256)
void k_moe_gemm1(const float* __restrict__ X, const float* __restrict__ W1,
                 const float* __restrict__ W3, float* __restrict__ Hx,
                 const int* __restrict__ offs, const int* __restrict__ idxg) {
    const int e = blockIdx.z;
    const int base = offs[e];
    const int cnt = offs[e + 1] - base;
    const int m0 = blockIdx.y * 64;
    if (m0 >= cnt) return;
    const int col0 = blockIdx.x * 64;
    __shared__ float As[16][64];
    __shared__ float B1s[16][64];
    __shared__ float B2s[16][64];
    const int tid = threadIdx.x;
    const int ty = tid >> 4, tx = tid & 15;
    const int arow = tid >> 2, acol = (tid & 3) << 2;
    const int brow = tid >> 4, bcol = (tid & 15) << 2;
    int gm = m0 + arow; if (gm > cnt - 1) gm = cnt - 1;
    const int token = idxg[base + gm];
    const float* Ap = X + (size_t)token * HDIM + acol;
    const float* B1p = W1 + (size_t)e * HDIM * ISZ + (size_t)brow * ISZ + col0 + bcol;
    const float* B2p = W3 + (size_t)e * HDIM * ISZ + (size_t)brow * ISZ + col0 + bcol;
    float acc1[4][4] = {}, acc2[4][4] = {};
    for (int k0 = 0; k0 < HDIM; k0 += 16) {
        float4 av = *(const float4*)(Ap + k0);
        float4 b1 = *(const float4*)(B1p + (size_t)k0 * ISZ);
        float4 b2 = *(const float4*)(B2p + (size_t)k0 * ISZ);
        __syncthreads();
        As[acol + 0][arow] = av.x; As[acol + 1][arow] = av.y;
        As[acol + 2][arow] = av.z; As[acol + 3][arow] = av.w;
        *(float4*)&B1s[brow][bcol] = b1;
        *(float4*)&B2s[brow][bcol] = b2;
        __syncthreads();
#pragma unroll
        for (int kk = 0; kk < 16; kk++) {
            float4 a4 = *(const float4*)&As[kk][ty << 2];
            float4 u4 = *(const float4*)&B1s[kk][tx << 2];
            float4 v4 = *(const float4*)&B2s[kk][tx << 2];
            float a_[4] = {a4.x, a4.y, a4.z, a4.w};
            float b_[4] = {u4.x, u4.y, u4.z, u4.w};
            float c_[4] = {v4.x, v4.y, v4.z, v4.w};
#pragma unroll
            for (int i = 0; i < 4; i++)
#pragma unroll
                for (int j = 0; j < 4; j++) {
                    acc1[i][j] = fmaf(a_[i], b_[j], acc1[i][j]);
                    acc2[i][j] = fmaf(a_[i], c_[j], acc2[i][j]);
                }
        }
    }
#pragma unroll
    for (int i = 0; i < 4; i++) {
        int m = m0 + (ty << 2) + i;
        if (m < cnt) {
            float4 hv;
            float g;
            g = acc1[i][0]; hv.x = (g / (1.0f + expf(-g))) * acc2[i][0];
            g = acc1[i][1]; hv.y = (g / (1.0f + expf(-g))) * acc2[i][1];
            g = acc1[i][2]; hv.z = (g / (1.0f + expf(-g))) * acc2[i][2];
            g = acc1[i][3]; hv.w = (g / (1.0f + expf(-g))) * acc2[i][3];
            *(float4*)(Hx + (size_t)(base + m) * ISZ + col0 + (tx << 2)) = hv;
        }
    }
}

// ---------------------------------------------------------------------------
// Grouped MoE GEMM2: OUT[token] += wt * (hexp_row @ w2[e]).
__global__ __launch_bounds__(256)
void k_moe_gemm2(const float* __restrict__ Hx, const float* __restrict__ W2,
                 float* __restrict__ OUT, const int* __restrict__ offs,
                 const int* __restrict__ idxg, const float* __restrict__ wtg) {
    const int e = blockIdx.z;
    const int base = offs[e];
    const int cnt = offs[e + 1] - base;
    const int m0 = blockIdx.y * 64;
    if (m0 >= cnt) return;
    const int col0 = blockIdx.x * 64;
    __shared__ float As[16][64];
    __shared__ float Bs[16][64];
    const int tid = threadIdx.x;
    const int ty = tid >> 4, tx = tid & 15;
    const int arow = tid >> 2, acol = (tid & 3) << 2;
    const int brow = tid >> 4, bcol = (tid & 15) << 2;
    int gm = m0 + arow; if (gm > cnt - 1) gm = cnt - 1;
    const float* Ap = Hx + (size_t)(base + gm) * ISZ + acol;
    const float* Bp = W2 + (size_t)e * ISZ * HDIM + (size_t)brow * HDIM + col0 + bcol;
    float acc[4][4] = {};
    for (int k0 = 0; k0 < ISZ; k0 += 16) {
        float4 av = *(const float4*)(Ap + k0);
        float4 bv = *(const float4*)(Bp + (size_t)k0 * HDIM);
        __syncthreads();
        As[acol + 0][arow] = av.x; As[acol + 1][arow] = av.y;
        As[acol + 2][arow] = av.z; As[acol + 3][arow] = av.w;
        *(float4*)&Bs[brow][bcol] = bv;
        __syncthreads();
#pragma unroll
        for (int kk = 0; kk < 16; kk++) {
            float4 a4 = *(const float4*)&As[kk][ty << 2];
            float4 b4 = *(const float4*)&Bs[kk][tx << 2];
            float a_[4] = {a4.x, a4.y, a4.z, a4.w};
            float b_[4] = {b4.x, b4.y, b4.z, b4.w};
#pragma unroll
            for (int i = 0; i < 4; i++)
#pragma unroll
                for (int j = 0; j < 4; j++)
                    acc[i][j] = fmaf(a_[i], b_[j], acc[i][j]);
        }
    }
#pragma unroll
    for (int i = 0; i < 4; i++) {
        int m = m0 + (ty << 2) + i;
        if (m < cnt) {
            int tok = idxg[base + m];
            float wt = wtg[base + m];
            float* dst = OUT + (size_t)tok * HDIM + col0 + (tx << 2);
            atomicAdd(dst + 0, wt * acc[i][0]);
            atomicAdd(dst + 1, wt * acc[i][1]);
            atomicAdd(dst + 2, wt * acc[i][2]);
            atomicAdd(dst + 3, wt * acc[i][3]);
        }
    }
}

// ===========================================================================
extern "C" void kernel_launch(void* const* d_in, const int* in_sizes, int n_in,
                              void* d_out, int out_size, void* d_ws,
                              size_t ws_size, hipStream_t stream) {
    (void)in_sizes; (void)n_in; (void)out_size; (void)ws_size;
    const float* hidden = (const float*)d_in[0];
    const int*   pos    = (const int*)d_in[1];
    const float* wq     = (const float*)d_in[2];
    const float* wk     = (const float*)d_in[3];
    const float* wv     = (const float*)d_in[4];
    const float* wo     = (const float*)d_in[5];
    const float* innw   = (const float*)d_in[6];
    const float* postnw = (const float*)d_in[7];
    const float* gatew  = (const float*)d_in[8];
    const float* w1     = (const float*)d_in[9];
    const float* w3     = (const float*)d_in[10];
    const float* w2     = (const float*)d_in[11];
    float* out = (float*)d_out;
    float* ws  = (float*)d_ws;

    const size_t TOK = (size_t)S_LEN * HDIM;       // 2,097,152
    float* xn = ws;
    int*   ib    = (int*)(ws + TOK);
    int*   cnt   = ib + 0;      // 8
    int*   offs  = ib + 16;     // 9
    int*   cur   = ib + 32;     // 8
    int*   top_i = ib + 64;     // 4096
    int*   idxg  = ib + 4160;   // 4096
    float* top_w = (float*)(ib + 8256);    // 4096
    float* wtg   = (float*)(ib + 12352);   // 4096
    float* big   = ws + TOK + 16448;
    float* q     = big;                     // 2M
    float* kbuf  = big + TOK;               // 0.5M
    float* vbuf  = kbuf + (size_t)S_LEN * NKVH * HD;
    float* attn  = vbuf + (size_t)S_LEN * NKVH * HD;
    float* hexp  = big;                     // reused after attention phase

    // 1) zero routing counters
    k_zero_ints<<<1, 64, 0, stream>>>(cnt, 64);
    // 2) rmsnorm -> xn
    k_rmsnorm<<<S_LEN, 256, 0, stream>>>(hidden, innw, xn);
    // 3) projections
    k_gemm<<<dim3(16, 32), 256, 0, stream>>>(xn, wq, nullptr, q, S_LEN, 1024, HDIM);
    k_gemm<<<dim3(4, 32), 256, 0, stream>>>(xn, wk, nullptr, kbuf, S_LEN, 256, HDIM);
    k_gemm<<<dim3(4, 32), 256, 0, stream>>>(xn, wv, nullptr, vbuf, S_LEN, 256, HDIM);
    // 4) rope in place
    k_rope<<<(S_LEN * (NHEAD + NKVH) * 32) / 256, 256, 0, stream>>>(q, kbuf, pos);
    // 5) attention -> attn
    k_attn<<<dim3(32, 16), 256, 0, stream>>>(q, kbuf, vbuf, attn);
    // 6) out = attn @ wo + hidden   ("h")
    k_gemm<<<dim3(16, 32), 256, 0, stream>>>(attn, wo, hidden, out, S_LEN, 1024, HDIM);
    // 7) rmsnorm(out) -> xn
    k_rmsnorm<<<S_LEN, 256, 0, stream>>>(out, postnw, xn);
    // 8-10) routing
    k_gate<<<S_LEN, 64, 0, stream>>>(xn, gatew, cnt, top_i, top_w);
    k_prefix<<<1, 1, 0, stream>>>(cnt, offs, cur);
    k_fill<<<S_LEN / 256, 256, 0, stream>>>(top_i, top_w, cur, idxg, wtg);
    // 11) grouped w1/w3 + silu*mul -> hexp
    k_moe_gemm1<<<dim3(ISZ / 64, 32, NEXP), 256, 0, stream>>>(xn, w1, w3, hexp,
                                                             offs, idxg);
    // 12) grouped w2, scatter-add into out
    k_moe_gemm2<<<dim3(HDIM / 64, 32, NEXP), 256, 0, stream>>>(hexp, w2, out,
                                                              offs, idxg, wtg);
}

// Round 2
// 1573.934 us; speedup vs baseline: 1.6951x; 1.6951x over previous
//
#include <hip/hip_runtime.h>
#include <math.h>

// ============================================================================
// MixtralDecoderLayer on MI355X — Round 1: bf16 MFMA for all GEMMs.
//
// Pipeline:
//   weight transpose+convert fp32->bf16 (per launch, ~528 MB traffic)
//   rmsnorm -> xnb(bf16)
//   qkv GEMM (MFMA, split epilogue) -> q/k/v fp32
//   rope (fp32, unchanged) ; flash attention (fp32, unchanged) -> attnb bf16
//   wo GEMM (MFMA, +hidden residual) -> d_out fp32
//   gate (fp32 from d_out, norm fused) ; route top-2 ; gather -> Xg bf16
//   MoE: w3-GEMM -> hg3 ; w1-GEMM with fused silu*hg3 -> he ; w2-GEMM -> oexp
//   combine: d_out += w0*oexp[s0] + w1*oexp[s1]
//
// GEMM core = m97 structure: 128x128 tile, BK=32, 4 waves x (4x4)
// mfma_f32_16x16x32_bf16, global_load_lds width=16, XOR-swizzled LDS
// (chunk ^= row&3) so staging and ds_read_b128 are bank-balanced.
//
// ws ~269 MB: w1t/w3t/w2t (176 MB) + qkvt/wot + xnb + {q,k,v,attnb | oexp}
// + Xg + hg3 + he + routing ints.
// ============================================================================

typedef unsigned short u16;
typedef unsigned int u32;
typedef __attribute__((ext_vector_type(8))) short s16x8;
typedef __attribute__((ext_vector_type(4))) float f32x4;

#define S_LEN 2048
#define HDIM  1024
#define NHEAD 16
#define NKVH  4
#define HD    64
#define ISZ   3584
#define NEXP  8
#define NSLOT 4096
#define EPS_F 1e-5f
#define NEG_INF -1e30f

__device__ __forceinline__ float bf2f(u16 u) {
    union { u32 i; float f; } c; c.i = ((u32)u) << 16; return c.f;
}
__device__ __forceinline__ u16 f2bf(float f) {
    union { float f; u32 i; } c; c.f = f;
    u32 r = (c.i + 0x7fffu + ((c.i >> 16) & 1u)) >> 16;
    return (u16)r;
}
__device__ __forceinline__ void async16(const u16* g, u16* l) {
    __builtin_amdgcn_global_load_lds(
        (const __attribute__((address_space(1))) void*)g,
        (__attribute__((address_space(3))) void*)l, 16, 0, 0);
}

// ---------------------------------------------------------------------------
__global__ void k_zero_ints(int* __restrict__ p, int n) {
    int i = blockIdx.x * blockDim.x + threadIdx.x;
    if (i < n) p[i] = 0;
}

// ---------------------------------------------------------------------------
// RMSNorm fp32 in -> bf16 out. One block per token.
__global__ __launch_bounds__(256)
void k_rmsnorm_bf(const float* __restrict__ x, const float* __restrict__ w,
                  u16* __restrict__ out) {
    int t = blockIdx.x;
    int tid = threadIdx.x;
    float4 v = ((const float4*)(x + (size_t)t * HDIM))[tid];
    float ss = v.x * v.x + v.y * v.y + v.z * v.z + v.w * v.w;
#pragma unroll
    for (int off = 32; off >= 1; off >>= 1) ss += __shfl_xor(ss, off, 64);
    __shared__ float red[4];
    if ((tid & 63) == 0) red[tid >> 6] = ss;
    __syncthreads();
    float tot = red[0] + red[1] + red[2] + red[3];
    float rstd = rsqrtf(tot * (1.0f / HDIM) + EPS_F);
    float4 wv = ((const float4*)w)[tid];
    uint2 pk;
    pk.x = (u32)f2bf(v.x * rstd * wv.x) | ((u32)f2bf(v.y * rstd * wv.y) << 16);
    pk.y = (u32)f2bf(v.z * rstd * wv.z) | ((u32)f2bf(v.w * rstd * wv.w) << 16);
    ((uint2*)(out + (size_t)t * HDIM))[tid] = pk;
}

// ---------------------------------------------------------------------------
// Transpose + convert: src fp32 [R][C] -> dst bf16 [C][R].  (per z: +strides)
// Block 256 = 4 waves; tile 64 cols (lane) x 128 rows (wave covers 32).
// Reads coalesced along C; each lane writes 64 contiguous bytes of one dst row.
__global__ __launch_bounds__(256)
void k_cvt_t(const float* __restrict__ src, u16* __restrict__ dst,
             int R, int C, long long srcZ, long long dstZ) {
    const int z = blockIdx.z;
    src += (size_t)z * srcZ;
    dst += (size_t)z * dstZ;
    const int lane = threadIdx.x & 63, w = threadIdx.x >> 6;
    const int c = blockIdx.x * 64 + lane;
    const int r0 = blockIdx.y * 128 + w * 32;
    float v[32];
#pragma unroll
    for (int i = 0; i < 32; i++) v[i] = src[(size_t)(r0 + i) * C + c];
#pragma unroll
    for (int g = 0; g < 4; g++) {
        uint4 pk;
        pk.x = (u32)f2bf(v[g * 8 + 0]) | ((u32)f2bf(v[g * 8 + 1]) << 16);
        pk.y = (u32)f2bf(v[g * 8 + 2]) | ((u32)f2bf(v[g * 8 + 3]) << 16);
        pk.z = (u32)f2bf(v[g * 8 + 4]) | ((u32)f2bf(v[g * 8 + 5]) << 16);
        pk.w = (u32)f2bf(v[g * 8 + 6]) | ((u32)f2bf(v[g * 8 + 7]) << 16);
        *(uint4*)(&dst[(size_t)c * R + r0 + g * 8]) = pk;
    }
}

// ---------------------------------------------------------------------------
// Shared MFMA GEMM core: C[128,128] tile of A[*,K] @ Bt[N,K]^T.
// rowA0..rowAmax clamps A-row reads (ragged MoE groups).
__device__ __forceinline__ void gemm128_loop(
    const u16* __restrict__ A, const u16* __restrict__ Bt, int K,
    int rowA0, int rowAmax, int n0, u16* lds, f32x4 acc[4][4]) {
    const int tid = threadIdx.x;
    const int lane = tid & 63, wid = tid >> 6;
    const int sr = lane >> 2, sc = lane & 3;
    const int ln = lane & 15, q = lane >> 4;
    const int wm = wid >> 1, wn = wid & 1;
    for (int k0 = 0; k0 < K; k0 += 32) {
        __syncthreads();
#pragma unroll
        for (int t = 0; t < 2; t++) {
            int row = wid * 32 + t * 16 + sr;
            int ck = (sc ^ (row & 3)) << 3;     // XOR swizzle, 8-elem chunks
            int ra = rowA0 + row;
            if (ra > rowAmax) ra = rowAmax;
            u16* ldsA = lds + (size_t)(wid * 32 + t * 16) * 32;
            u16* ldsB = ldsA + 4096;
            async16(A + (size_t)ra * K + k0 + ck, ldsA);
            async16(Bt + (size_t)(n0 + row) * K + k0 + ck, ldsB);
        }
        __syncthreads();
        s16x8 af[4], bfv[4];
#pragma unroll
        for (int i = 0; i < 4; i++) {
            int ar = wm * 64 + i * 16 + ln;
            af[i] = *(const s16x8*)(lds + ar * 32 + ((q ^ (ar & 3)) << 3));
            int br = wn * 64 + i * 16 + ln;
            bfv[i] = *(const s16x8*)(lds + 4096 + br * 32 + ((q ^ (br & 3)) << 3));
        }
#pragma unroll
        for (int i = 0; i < 4; i++)
#pragma unroll
            for (int j = 0; j < 4; j++)
                acc[i][j] = __builtin_amdgcn_mfma_f32_16x16x32_bf16(
                    af[i], bfv[j], acc[i][j], 0, 0, 0);
    }
}

// ---------------------------------------------------------------------------
// Flat GEMM.  mode 0: fp32->F0 | 1: bf16->O16 | 2: fp32+RES->F0 |
//             3: qkv split -> F0(q,1024) F1(k,256) F2(v,256)
__global__ __launch_bounds__(256, 2)
void k_gemm_bt(const u16* __restrict__ A, const u16* __restrict__ Bt,
               int M, int N, int K, int mode,
               float* __restrict__ F0, float* __restrict__ F1,
               float* __restrict__ F2, const float* __restrict__ RES,
               u16* __restrict__ O16) {
    __shared__ u16 lds[8192];
    const int m0 = blockIdx.y * 128, n0 = blockIdx.x * 128;
    f32x4 acc[4][4];
#pragma unroll
    for (int i = 0; i < 4; i++)
#pragma unroll
        for (int j = 0; j < 4; j++) acc[i][j] = (f32x4){0.f, 0.f, 0.f, 0.f};
    gemm128_loop(A, Bt, K, m0, M - 1, n0, lds, acc);
    const int lane = threadIdx.x & 63, wid = threadIdx.x >> 6;
    const int ln = lane & 15, q = lane >> 4, wm = wid >> 1, wn = wid & 1;
#pragma unroll
    for (int i = 0; i < 4; i++) {
#pragma unroll
        for (int r = 0; r < 4; r++) {
            int m = m0 + wm * 64 + i * 16 + q * 4 + r;
#pragma unroll
            for (int j = 0; j < 4; j++) {
                int n = n0 + wn * 64 + j * 16 + ln;
                float v = acc[i][j][r];
                if (mode == 0) {
                    F0[(size_t)m * N + n] = v;
                } else if (mode == 1) {
                    O16[(size_t)m * N + n] = f2bf(v);
                } else if (mode == 2) {
                    F0[(size_t)m * N + n] = v + RES[(size_t)m * N + n];
                } else {
                    if (n < 1024)       F0[(size_t)m * 1024 + n] = v;
                    else if (n < 1280)  F1[(size_t)m * 256 + (n - 1024)] = v;
                    else                F2[(size_t)m * 256 + (n - 1280)] = v;
                }
            }
        }
    }
}

// ---------------------------------------------------------------------------
// Grouped MoE GEMM.  mode 0: fp32->F0 | 1: bf16->O16 | 2: silu(acc)*AUX->O16
__global__ __launch_bounds__(256, 2)
void k_gemm_bt_moe(const u16* __restrict__ A, const u16* __restrict__ WT,
                   int N, int K, int mode,
                   float* __restrict__ F0, u16* __restrict__ O16,
                   const u16* __restrict__ AUX, const int* __restrict__ offs) {
    const int e = blockIdx.z;
    const int base = offs[e], cnt = offs[e + 1] - base;
    const int m0 = blockIdx.y * 128;
    if (m0 >= cnt) return;
    __shared__ u16 lds[8192];
    const u16* Bt = WT + (size_t)e * N * K;
    const int n0 = blockIdx.x * 128;
    f32x4 acc[4][4];
#pragma unroll
    for (int i = 0; i < 4; i++)
#pragma unroll
        for (int j = 0; j < 4; j++) acc[i][j] = (f32x4){0.f, 0.f, 0.f, 0.f};
    gemm128_loop(A, Bt, K, base + m0, NSLOT - 1, n0, lds, acc);
    const int lane = threadIdx.x & 63, wid = threadIdx.x >> 6;
    const int ln = lane & 15, q = lane >> 4, wm = wid >> 1, wn = wid & 1;
#pragma unroll
    for (int i = 0; i < 4; i++) {
#pragma unroll
        for (int r = 0; r < 4; r++) {
            int mloc = wm * 64 + i * 16 + q * 4 + r;
            if (m0 + mloc >= cnt) continue;
            size_t row = (size_t)(base + m0 + mloc);
#pragma unroll
            for (int j = 0; j < 4; j++) {
                int n = n0 + wn * 64 + j * 16 + ln;
                float v = acc[i][j][r];
                if (mode == 0) {
                    F0[row * N + n] = v;
                } else if (mode == 1) {
                    O16[row * N + n] = f2bf(v);
                } else {
                    float a = bf2f(AUX[row * N + n]);
                    float s = v / (1.0f + expf(-v));
                    O16[row * N + n] = f2bf(s * a);
                }
            }
        }
    }
}

// ---------------------------------------------------------------------------
// RoPE in place on q [S][NH*HD] and k [S][NKV*HD] (fp32).
__global__ __launch_bounds__(256)
void k_rope(float* __restrict__ q, float* __restrict__ k,
            const int* __restrict__ pos) {
    int id = blockIdx.x * blockDim.x + threadIdx.x;
    int d = id & 31;
    int hh = (id >> 5) % (NHEAD + NKVH);
    int s = id / ((NHEAD + NKVH) * 32);
    float p = (float)pos[s];
    float inv = exp2f(-((float)(2 * d) / (float)HD) * log2f(1.0e6f));
    float ang = p * inv;
    float c = cosf(ang), sn = sinf(ang);
    float* ptr = (hh < NHEAD)
                     ? (q + (size_t)s * (NHEAD * HD) + hh * HD)
                     : (k + (size_t)s * (NKVH * HD) + (hh - NHEAD) * HD);
    float x1 = ptr[d], x2 = ptr[d + 32];
    ptr[d]      = x1 * c - x2 * sn;
    ptr[d + 32] = x2 * c + x1 * sn;
}

// ---------------------------------------------------------------------------
// Flash attention (fp32, unchanged from round 0) -> bf16 output.
__device__ __forceinline__ float4 ld4sw(const float* t, int r, int c4) {
    return *(const float4*)&t[r * 64 + (((c4 + r) & 15) << 2)];
}
__device__ __forceinline__ void st4sw(float* t, int r, int c4, float4 v) {
    *(float4*)&t[r * 64 + (((c4 + r) & 15) << 2)] = v;
}

__global__ __launch_bounds__(256)
void k_attn(const float* __restrict__ q, const float* __restrict__ kb,
            const float* __restrict__ vb, u16* __restrict__ ob) {
    __shared__ float Qt[64 * 64];
    __shared__ float Kt[64 * 64];
    __shared__ float Vt[64 * 64];
    __shared__ float Pst[64 * 64];
    const int qt = blockIdx.x, h = blockIdx.y;
    const int kvh = h >> 2;
    const int tid = threadIdx.x;
    const int rgrp = tid >> 4, cgrp = tid & 15;
    const int lrow = tid >> 4, ld4 = tid & 15;

#pragma unroll
    for (int rr = 0; rr < 4; rr++) {
        int r = lrow + rr * 16;
        float4 val = *(const float4*)(q + (size_t)(qt * 64 + r) * HDIM +
                                      h * HD + ld4 * 4);
        st4sw(Qt, r, ld4, val);
    }
    float mI[4], lI[4], O[4][4];
#pragma unroll
    for (int i = 0; i < 4; i++) {
        mI[i] = NEG_INF; lI[i] = 0.0f;
#pragma unroll
        for (int j = 0; j < 4; j++) O[i][j] = 0.0f;
    }

    for (int kt = 0; kt <= qt; kt++) {
        __syncthreads();
#pragma unroll
        for (int rr = 0; rr < 4; rr++) {
            int r = lrow + rr * 16;
            size_t gro = (size_t)(kt * 64 + r) * (NKVH * HD) + kvh * HD + ld4 * 4;
            st4sw(Kt, r, ld4, *(const float4*)(kb + gro));
            st4sw(Vt, r, ld4, *(const float4*)(vb + gro));
        }
        __syncthreads();

        float s[4][4] = {};
#pragma unroll
        for (int d4 = 0; d4 < 16; d4++) {
            float4 qv[4];
#pragma unroll
            for (int i = 0; i < 4; i++) qv[i] = ld4sw(Qt, rgrp * 4 + i, d4);
#pragma unroll
            for (int j = 0; j < 4; j++) {
                float4 kv = ld4sw(Kt, cgrp + 16 * j, d4);
#pragma unroll
                for (int i = 0; i < 4; i++) {
                    s[i][j] = fmaf(qv[i].x, kv.x, s[i][j]);
                    s[i][j] = fmaf(qv[i].y, kv.y, s[i][j]);
                    s[i][j] = fmaf(qv[i].z, kv.z, s[i][j]);
                    s[i][j] = fmaf(qv[i].w, kv.w, s[i][j]);
                }
            }
        }
        const bool diag = (kt == qt);
        float mt[4];
#pragma unroll
        for (int i = 0; i < 4; i++) {
#pragma unroll
            for (int j = 0; j < 4; j++) {
                s[i][j] *= 0.125f;
                if (diag && (cgrp + 16 * j) > (rgrp * 4 + i)) s[i][j] = NEG_INF;
            }
            mt[i] = fmaxf(fmaxf(s[i][0], s[i][1]), fmaxf(s[i][2], s[i][3]));
        }
#pragma unroll
        for (int off = 8; off >= 1; off >>= 1)
#pragma unroll
            for (int i = 0; i < 4; i++)
                mt[i] = fmaxf(mt[i], __shfl_xor(mt[i], off, 64));

        float rs[4];
#pragma unroll
        for (int i = 0; i < 4; i++) {
            float mn = fmaxf(mI[i], mt[i]);
            float alpha = expf(mI[i] - mn);
            mI[i] = mn;
            float r0 = 0.0f;
#pragma unroll
            for (int j = 0; j < 4; j++) {
                s[i][j] = expf(s[i][j] - mn);
                r0 += s[i][j];
            }
            rs[i] = r0;
            lI[i] *= alpha;
#pragma unroll
            for (int jd = 0; jd < 4; jd++) O[i][jd] *= alpha;
        }
#pragma unroll
        for (int off = 8; off >= 1; off >>= 1)
#pragma unroll
            for (int i = 0; i < 4; i++) rs[i] += __shfl_xor(rs[i], off, 64);
#pragma unroll
        for (int i = 0; i < 4; i++) lI[i] += rs[i];

#pragma unroll
        for (int i = 0; i < 4; i++) {
            int r = rgrp * 4 + i;
#pragma unroll
            for (int j = 0; j < 4; j++) {
                int c = cgrp + 16 * j;
                Pst[r * 64 + ((c + 4 * r) & 63)] = s[i][j];
            }
        }
        __syncthreads();

#pragma unroll
        for (int c4 = 0; c4 < 16; c4++) {
            float pv[4][4];
#pragma unroll
            for (int i = 0; i < 4; i++) {
                float4 p4 = ld4sw(Pst, rgrp * 4 + i, c4);
                pv[i][0] = p4.x; pv[i][1] = p4.y; pv[i][2] = p4.z; pv[i][3] = p4.w;
            }
#pragma unroll
            for (int cc = 0; cc < 4; cc++) {
                int c = c4 * 4 + cc;
                float4 vv = ld4sw(Vt, c, cgrp);
                float v_[4] = {vv.x, vv.y, vv.z, vv.w};
#pragma unroll
                for (int i = 0; i < 4; i++)
#pragma unroll
                    for (int jd = 0; jd < 4; jd++)
                        O[i][jd] = fmaf(pv[i][cc], v_[jd], O[i][jd]);
            }
        }
    }

#pragma unroll
    for (int i = 0; i < 4; i++) {
        float inv = 1.0f / lI[i];
        int gq = qt * 64 + rgrp * 4 + i;
        uint2 pk;
        pk.x = (u32)f2bf(O[i][0] * inv) | ((u32)f2bf(O[i][1] * inv) << 16);
        pk.y = (u32)f2bf(O[i][2] * inv) | ((u32)f2bf(O[i][3] * inv) << 16);
        *(uint2*)(ob + (size_t)gq * HDIM + h * HD + cgrp * 4) = pk;
    }
}

// ---------------------------------------------------------------------------
// Gate with fused post-norm: logits_e = rstd * sum_h (h[i]*pw[i]*G[i][e]).
// fp32 inputs so top-2 selection matches the fp32 reference.
__global__ __launch_bounds__(64)
void k_gate(const float* __restrict__ Hst, const float* __restrict__ PW,
            const float* __restrict__ GW, int* __restrict__ cnt,
            int* __restrict__ top_i, float* __restrict__ top_w) {
    int t = blockIdx.x;
    int lane = threadIdx.x;
    const float* hrow = Hst + (size_t)t * HDIM;
    float ss = 0.0f;
    float acc[NEXP] = {};
    for (int hh = lane; hh < HDIM; hh += 64) {
        float hv = hrow[hh];
        ss += hv * hv;
        float xw = hv * PW[hh];
        const float* g = GW + (size_t)hh * NEXP;
#pragma unroll
        for (int e = 0; e < NEXP; e++) acc[e] += xw * g[e];
    }
#pragma unroll
    for (int off = 32; off >= 1; off >>= 1) {
        ss += __shfl_xor(ss, off, 64);
#pragma unroll
        for (int e = 0; e < NEXP; e++) acc[e] += __shfl_xor(acc[e], off, 64);
    }
    if (lane == 0) {
        float rstd = rsqrtf(ss * (1.0f / HDIM) + EPS_F);
        int e0 = 0;
        for (int e = 1; e < NEXP; e++) if (acc[e] > acc[e0]) e0 = e;
        int e1 = (e0 == 0) ? 1 : 0;
        for (int e = 0; e < NEXP; e++)
            if (e != e0 && acc[e] > acc[e1]) e1 = e;
        float w0 = 1.0f / (1.0f + expf((acc[e1] - acc[e0]) * rstd));
        top_i[t * 2 + 0] = e0; top_i[t * 2 + 1] = e1;
        top_w[t * 2 + 0] = w0; top_w[t * 2 + 1] = 1.0f - w0;
        atomicAdd(&cnt[e0], 1);
        atomicAdd(&cnt[e1], 1);
    }
}

__global__ void k_prefix(const int* __restrict__ cnt, int* __restrict__ offs,
                         int* __restrict__ cur) {
    if (blockIdx.x == 0 && threadIdx.x == 0) {
        int a = 0;
        for (int e = 0; e < NEXP; e++) { offs[e] = a; cur[e] = a; a += cnt[e]; }
        offs[NEXP] = a;
    }
}

__global__ __launch_bounds__(256)
void k_fill(const int* __restrict__ top_i, int* __restrict__ cur,
            int* __restrict__ idxg, int* __restrict__ slot) {
    int t = blockIdx.x * blockDim.x + threadIdx.x;
    if (t >= S_LEN) return;
#pragma unroll
    for (int kk = 0; kk < 2; kk++) {
        int e = top_i[t * 2 + kk];
        int p = atomicAdd(&cur[e], 1);
        idxg[p] = t;
        slot[t * 2 + kk] = p;
    }
}

__global__ __launch_bounds__(256)
void k_gather(const u16* __restrict__ xnb, const int* __restrict__ idxg,
              u16* __restrict__ Xg) {
    int p = blockIdx.x;
    int t = idxg[p];
    const uint2* s = (const uint2*)(xnb + (size_t)t * HDIM);
    uint2* d = (uint2*)(Xg + (size_t)p * HDIM);
    d[threadIdx.x] = s[threadIdx.x];
}

__global__ __launch_bounds__(256)
void k_combine(const float* __restrict__ oexp, const int* __restrict__ slot,
               const float* __restrict__ top_w, float* __restrict__ out) {
    int t = blockIdx.x, tid = threadIdx.x;
    int s0 = slot[t * 2], s1 = slot[t * 2 + 1];
    float w0 = top_w[t * 2], w1 = top_w[t * 2 + 1];
    float4 a = ((const float4*)(oexp + (size_t)s0 * HDIM))[tid];
    float4 b = ((const float4*)(oexp + (size_t)s1 * HDIM))[tid];
    float4* o = (float4*)(out + (size_t)t * HDIM);
    float4 c = o[tid];
    c.x += w0 * a.x + w1 * b.x;
    c.y += w0 * a.y + w1 * b.y;
    c.z += w0 * a.z + w1 * b.z;
    c.w += w0 * a.w + w1 * b.w;
    o[tid] = c;
}

// ===========================================================================
extern "C" void kernel_launch(void* const* d_in, const int* in_sizes, int n_in,
                              void* d_out, int out_size, void* d_ws,
                              size_t ws_size, hipStream_t stream) {
    (void)in_sizes; (void)n_in; (void)out_size; (void)ws_size;
    const float* hidden = (const float*)d_in[0];
    const int*   pos    = (const int*)d_in[1];
    const float* wq     = (const float*)d_in[2];
    const float* wk     = (const float*)d_in[3];
    const float* wv     = (const float*)d_in[4];
    const float* wo     = (const float*)d_in[5];
    const float* innw   = (const float*)d_in[6];
    const float* postnw = (const float*)d_in[7];
    const float* gatew  = (const float*)d_in[8];
    const float* w1     = (const float*)d_in[9];
    const float* w3     = (const float*)d_in[10];
    const float* w2     = (const float*)d_in[11];
    float* out = (float*)d_out;

    // ---- workspace layout (bf16 = u16), ~269 MB ----
    u16* w1t  = (u16*)d_ws;
    u16* w3t  = w1t + (size_t)NEXP * ISZ * HDIM;
    u16* w2t  = w3t + (size_t)NEXP * ISZ * HDIM;
    u16* qkvt = w2t + (size_t)NEXP * ISZ * HDIM;
    u16* wot  = qkvt + (size_t)1536 * HDIM;
    u16* xnb  = wot + (size_t)HDIM * HDIM;
    float* qbuf = (float*)(xnb + (size_t)S_LEN * HDIM);
    float* kbuf = qbuf + (size_t)S_LEN * HDIM;
    float* vbuf = kbuf + (size_t)S_LEN * NKVH * HD;
    u16*   attnb = (u16*)(vbuf + (size_t)S_LEN * NKVH * HD);
    float* oexp = qbuf;   // overlay: q/k/v/attnb dead before oexp written
    u16* Xg  = attnb + (size_t)S_LEN * HDIM;
    u16* hg3 = Xg + (size_t)NSLOT * HDIM;
    u16* he  = hg3 + (size_t)NSLOT * ISZ;
    int* ib  = (int*)(he + (size_t)NSLOT * ISZ);
    int*   cnt   = ib;
    int*   offs  = ib + 16;
    int*   cur   = ib + 32;
    int*   top_i = ib + 64;
    int*   slot  = ib + 64 + 4096;
    int*   idxg  = ib + 64 + 8192;
    float* top_w = (float*)(ib + 64 + 12288);

    const long long HI = (long long)HDIM * ISZ;

    k_zero_ints<<<1, 64, 0, stream>>>(cnt, 64);
    k_rmsnorm_bf<<<S_LEN, 256, 0, stream>>>(hidden, innw, xnb);

    // weight transpose+convert
    k_cvt_t<<<dim3(16, 8, 1), 256, 0, stream>>>(wq, qkvt, 1024, 1024, 0, 0);
    k_cvt_t<<<dim3(4, 8, 1), 256, 0, stream>>>(wk, qkvt + (size_t)1024 * 1024, 1024, 256, 0, 0);
    k_cvt_t<<<dim3(4, 8, 1), 256, 0, stream>>>(wv, qkvt + (size_t)1280 * 1024, 1024, 256, 0, 0);
    k_cvt_t<<<dim3(16, 8, 1), 256, 0, stream>>>(wo, wot, 1024, 1024, 0, 0);
    k_cvt_t<<<dim3(56, 8, NEXP), 256, 0, stream>>>(w1, w1t, 1024, 3584, HI, HI);
    k_cvt_t<<<dim3(56, 8, NEXP), 256, 0, stream>>>(w3, w3t, 1024, 3584, HI, HI);
    k_cvt_t<<<dim3(16, 28, NEXP), 256, 0, stream>>>(w2, w2t, 3584, 1024, HI, HI);

    // qkv projection (split epilogue) -> fp32 q/k/v
    k_gemm_bt<<<dim3(12, 16), 256, 0, stream>>>(xnb, qkvt, 2048, 1536, 1024, 3,
                                                qbuf, kbuf, vbuf, nullptr, nullptr);
    k_rope<<<(S_LEN * (NHEAD + NKVH) * 32) / 256, 256, 0, stream>>>(qbuf, kbuf, pos);
    k_attn<<<dim3(32, 16), 256, 0, stream>>>(qbuf, kbuf, vbuf, attnb);
    // wo + residual -> d_out (h)
    k_gemm_bt<<<dim3(8, 16), 256, 0, stream>>>(attnb, wot, 2048, 1024, 1024, 2,
                                               out, nullptr, nullptr, hidden, nullptr);
    // post-norm -> xnb ; gate from fp32 h (norm fused)
    k_rmsnorm_bf<<<S_LEN, 256, 0, stream>>>(out, postnw, xnb);
    k_gate<<<S_LEN, 64, 0, stream>>>(out, postnw, gatew, cnt, top_i, top_w);
    k_prefix<<<1, 1, 0, stream>>>(cnt, offs, cur);
    k_fill<<<S_LEN / 256, 256, 0, stream>>>(top_i, cur, idxg, slot);
    k_gather<<<NSLOT, 256, 0, stream>>>(xnb, idxg, Xg);

    // MoE grouped GEMMs
    k_gemm_bt_moe<<<dim3(28, 16, NEXP), 256, 0, stream>>>(Xg, w3t, 3584, 1024, 1,
                                                          nullptr, hg3, nullptr, offs);
    k_gemm_bt_moe<<<dim3(28, 16, NEXP), 256, 0, stream>>>(Xg, w1t, 3584, 1024, 2,
                                                          nullptr, he, hg3, offs);
    k_gemm_bt_moe<<<dim3(8, 16, NEXP), 256, 0, stream>>>(he, w2t, 1024, 3584, 0,
                                                         oexp, nullptr, nullptr, offs);
    k_combine<<<S_LEN, 256, 0, stream>>>(oexp, slot, top_w, out);
}

// Round 4
// 1000.498 us; speedup vs baseline: 2.6666x; 1.5732x over previous
//
#include <hip/hip_runtime.h>
#include <math.h>

// ============================================================================
// MixtralDecoderLayer on MI355X — Round 3: fp16 MFMA flash attention.
//
//   rmsnorm -> xnb(bf16)
//   weight cvt fp32->bf16 transposed (round-2-verified k_cvt_t)
//   qkv GEMM -> q,k fp32 + v fp16 ; rope+cvt -> qb2,kb2 fp16
//   MFMA flash attention (fp16 in, fp32 accum, 32KB LDS) -> attnb bf16
//   wo GEMM (+hidden) -> d_out ; gate/route (fp32) ; gather
//   MoE grouped GEMMs (m97 structure, bf16) ; combine
// ============================================================================

typedef unsigned short u16;
typedef unsigned int u32;
typedef __attribute__((ext_vector_type(8))) short s16x8;
typedef __attribute__((ext_vector_type(8))) _Float16 f16x8;
typedef __attribute__((ext_vector_type(4))) float f32x4;

#define S_LEN 2048
#define HDIM  1024
#define NHEAD 16
#define NKVH  4
#define HD    64
#define ISZ   3584
#define NEXP  8
#define NSLOT 4096
#define EPS_F 1e-5f
#define NEG_INF -1e30f
#define LOG2E 1.44269504f

__device__ __forceinline__ float bf2f(u16 u) {
    union { u32 i; float f; } c; c.i = ((u32)u) << 16; return c.f;
}
__device__ __forceinline__ u16 f2bf(float f) {
    union { float f; u32 i; } c; c.f = f;
    u32 r = (c.i + 0x7fffu + ((c.i >> 16) & 1u)) >> 16;
    return (u16)r;
}
__device__ __forceinline__ u16 f2h_bits(float f) {
    union { _Float16 h; u16 u; } c; c.h = (_Float16)f; return c.u;
}
__device__ __forceinline__ void async16(const u16* g, u16* l) {
    __builtin_amdgcn_global_load_lds(
        (const __attribute__((address_space(1))) void*)g,
        (__attribute__((address_space(3))) void*)l, 16, 0, 0);
}

// ---------------------------------------------------------------------------
__global__ void k_zero_ints(int* __restrict__ p, int n) {
    int i = blockIdx.x * blockDim.x + threadIdx.x;
    if (i < n) p[i] = 0;
}

// ---------------------------------------------------------------------------
__global__ __launch_bounds__(256)
void k_rmsnorm_bf(const float* __restrict__ x, const float* __restrict__ w,
                  u16* __restrict__ out) {
    int t = blockIdx.x;
    int tid = threadIdx.x;
    float4 v = ((const float4*)(x + (size_t)t * HDIM))[tid];
    float ss = v.x * v.x + v.y * v.y + v.z * v.z + v.w * v.w;
#pragma unroll
    for (int off = 32; off >= 1; off >>= 1) ss += __shfl_xor(ss, off, 64);
    __shared__ float red[4];
    if ((tid & 63) == 0) red[tid >> 6] = ss;
    __syncthreads();
    float tot = red[0] + red[1] + red[2] + red[3];
    float rstd = rsqrtf(tot * (1.0f / HDIM) + EPS_F);
    float4 wv = ((const float4*)w)[tid];
    uint2 pk;
    pk.x = (u32)f2bf(v.x * rstd * wv.x) | ((u32)f2bf(v.y * rstd * wv.y) << 16);
    pk.y = (u32)f2bf(v.z * rstd * wv.z) | ((u32)f2bf(v.w * rstd * wv.w) << 16);
    ((uint2*)(out + (size_t)t * HDIM))[tid] = pk;
}

// ---------------------------------------------------------------------------
// Transpose + convert (round-2-verified): src fp32 [R][C] -> dst bf16 [C][R].
__global__ __launch_bounds__(256)
void k_cvt_t(const float* __restrict__ src, u16* __restrict__ dst,
             int R, int C, long long srcZ, long long dstZ) {
    const int z = blockIdx.z;
    src += (size_t)z * srcZ;
    dst += (size_t)z * dstZ;
    const int lane = threadIdx.x & 63, w = threadIdx.x >> 6;
    const int c = blockIdx.x * 64 + lane;
    const int r0 = blockIdx.y * 128 + w * 32;
    float v[32];
#pragma unroll
    for (int i = 0; i < 32; i++) v[i] = src[(size_t)(r0 + i) * C + c];
#pragma unroll
    for (int g = 0; g < 4; g++) {
        uint4 pk;
        pk.x = (u32)f2bf(v[g * 8 + 0]) | ((u32)f2bf(v[g * 8 + 1]) << 16);
        pk.y = (u32)f2bf(v[g * 8 + 2]) | ((u32)f2bf(v[g * 8 + 3]) << 16);
        pk.z = (u32)f2bf(v[g * 8 + 4]) | ((u32)f2bf(v[g * 8 + 5]) << 16);
        pk.w = (u32)f2bf(v[g * 8 + 6]) | ((u32)f2bf(v[g * 8 + 7]) << 16);
        *(uint4*)(&dst[(size_t)c * R + r0 + g * 8]) = pk;
    }
}

// ---------------------------------------------------------------------------
// Shared MFMA GEMM core: 128x128 tile, BK=32, global_load_lds staging.
__device__ __forceinline__ void gemm128_loop(
    const u16* __restrict__ A, const u16* __restrict__ Bt, int K,
    int rowA0, int rowAmax, int n0, u16* lds, f32x4 acc[4][4]) {
    const int tid = threadIdx.x;
    const int lane = tid & 63, wid = tid >> 6;
    const int sr = lane >> 2, sc = lane & 3;
    const int ln = lane & 15, q = lane >> 4;
    const int wm = wid >> 1, wn = wid & 1;
    for (int k0 = 0; k0 < K; k0 += 32) {
        __syncthreads();
#pragma unroll
        for (int t = 0; t < 2; t++) {
            int row = wid * 32 + t * 16 + sr;
            int ck = (sc ^ (row & 3)) << 3;
            int ra = rowA0 + row;
            if (ra > rowAmax) ra = rowAmax;
            u16* ldsA = lds + (size_t)(wid * 32 + t * 16) * 32;
            u16* ldsB = ldsA + 4096;
            async16(A + (size_t)ra * K + k0 + ck, ldsA);
            async16(Bt + (size_t)(n0 + row) * K + k0 + ck, ldsB);
        }
        __syncthreads();
        s16x8 af[4], bfv[4];
#pragma unroll
        for (int i = 0; i < 4; i++) {
            int ar = wm * 64 + i * 16 + ln;
            af[i] = *(const s16x8*)(lds + ar * 32 + ((q ^ (ar & 3)) << 3));
            int br = wn * 64 + i * 16 + ln;
            bfv[i] = *(const s16x8*)(lds + 4096 + br * 32 + ((q ^ (br & 3)) << 3));
        }
#pragma unroll
        for (int i = 0; i < 4; i++)
#pragma unroll
            for (int j = 0; j < 4; j++)
                acc[i][j] = __builtin_amdgcn_mfma_f32_16x16x32_bf16(
                    af[i], bfv[j], acc[i][j], 0, 0, 0);
    }
}

// ---------------------------------------------------------------------------
// Flat GEMM.  mode 0: fp32->F0 | 1: bf16->O16 | 2: fp32+RES->F0 |
//             3: qkv split -> F0(q fp32) F1(k fp32) O16(v fp16 bits)
__global__ __launch_bounds__(256, 2)
void k_gemm_bt(const u16* __restrict__ A, const u16* __restrict__ Bt,
               int M, int N, int K, int mode,
               float* __restrict__ F0, float* __restrict__ F1,
               const float* __restrict__ RES, u16* __restrict__ O16) {
    __shared__ u16 lds[8192];
    const int m0 = blockIdx.y * 128, n0 = blockIdx.x * 128;
    f32x4 acc[4][4];
#pragma unroll
    for (int i = 0; i < 4; i++)
#pragma unroll
        for (int j = 0; j < 4; j++) acc[i][j] = (f32x4){0.f, 0.f, 0.f, 0.f};
    gemm128_loop(A, Bt, K, m0, M - 1, n0, lds, acc);
    const int lane = threadIdx.x & 63, wid = threadIdx.x >> 6;
    const int ln = lane & 15, q = lane >> 4, wm = wid >> 1, wn = wid & 1;
#pragma unroll
    for (int i = 0; i < 4; i++) {
#pragma unroll
        for (int r = 0; r < 4; r++) {
            int m = m0 + wm * 64 + i * 16 + q * 4 + r;
#pragma unroll
            for (int j = 0; j < 4; j++) {
                int n = n0 + wn * 64 + j * 16 + ln;
                float v = acc[i][j][r];
                if (mode == 0) {
                    F0[(size_t)m * N + n] = v;
                } else if (mode == 1) {
                    O16[(size_t)m * N + n] = f2bf(v);
                } else if (mode == 2) {
                    F0[(size_t)m * N + n] = v + RES[(size_t)m * N + n];
                } else {
                    if (n < 1024)       F0[(size_t)m * 1024 + n] = v;
                    else if (n < 1280)  F1[(size_t)m * 256 + (n - 1024)] = v;
                    else                O16[(size_t)m * 256 + (n - 1280)] = f2h_bits(v);
                }
            }
        }
    }
}

// ---------------------------------------------------------------------------
// Grouped MoE GEMM.  mode 0: fp32->F0 | 1: bf16->O16 | 2: silu(acc)*AUX->O16
__global__ __launch_bounds__(256, 2)
void k_gemm_bt_moe(const u16* __restrict__ A, const u16* __restrict__ WT,
                   int N, int K, int mode,
                   float* __restrict__ F0, u16* __restrict__ O16,
                   const u16* __restrict__ AUX, const int* __restrict__ offs) {
    const int e = blockIdx.z;
    const int base = offs[e], cnt = offs[e + 1] - base;
    const int m0 = blockIdx.y * 128;
    if (m0 >= cnt) return;
    __shared__ u16 lds[8192];
    const u16* Bt = WT + (size_t)e * N * K;
    const int n0 = blockIdx.x * 128;
    f32x4 acc[4][4];
#pragma unroll
    for (int i = 0; i < 4; i++)
#pragma unroll
        for (int j = 0; j < 4; j++) acc[i][j] = (f32x4){0.f, 0.f, 0.f, 0.f};
    gemm128_loop(A, WT + (size_t)e * N * K, K, base + m0, NSLOT - 1, n0, lds, acc);
    (void)Bt;
    const int lane = threadIdx.x & 63, wid = threadIdx.x >> 6;
    const int ln = lane & 15, q = lane >> 4, wm = wid >> 1, wn = wid & 1;
#pragma unroll
    for (int i = 0; i < 4; i++) {
#pragma unroll
        for (int r = 0; r < 4; r++) {
            int mloc = wm * 64 + i * 16 + q * 4 + r;
            if (m0 + mloc >= cnt) continue;
            size_t row = (size_t)(base + m0 + mloc);
#pragma unroll
            for (int j = 0; j < 4; j++) {
                int n = n0 + wn * 64 + j * 16 + ln;
                float v = acc[i][j][r];
                if (mode == 0) {
                    F0[row * N + n] = v;
                } else if (mode == 1) {
                    O16[row * N + n] = f2bf(v);
                } else {
                    float a = bf2f(AUX[row * N + n]);
                    float s = v / (1.0f + expf(-v));
                    O16[row * N + n] = f2bf(s * a);
                }
            }
        }
    }
}

// ---------------------------------------------------------------------------
// RoPE + convert to fp16 bits: q fp32 [S][1024] -> qb2; k fp32 [S][256] -> kb2.
__global__ __launch_bounds__(256)
void k_rope_cvt(const float* __restrict__ q, const float* __restrict__ k,
                const int* __restrict__ pos, u16* __restrict__ qb2,
                u16* __restrict__ kb2) {
    int id = blockIdx.x * blockDim.x + threadIdx.x;
    int d = id & 31;
    int hh = (id >> 5) % (NHEAD + NKVH);
    int s = id / ((NHEAD + NKVH) * 32);
    float p = (float)pos[s];
    float inv = exp2f(-((float)(2 * d) / (float)HD) * log2f(1.0e6f));
    float ang = p * inv;
    float c = cosf(ang), sn = sinf(ang);
    const float* sp; u16* dp;
    if (hh < NHEAD) {
        sp = q + (size_t)s * (NHEAD * HD) + hh * HD;
        dp = qb2 + (size_t)s * (NHEAD * HD) + hh * HD;
    } else {
        sp = k + (size_t)s * (NKVH * HD) + (hh - NHEAD) * HD;
        dp = kb2 + (size_t)s * (NKVH * HD) + (hh - NHEAD) * HD;
    }
    float x1 = sp[d], x2 = sp[d + 32];
    dp[d]      = f2h_bits(x1 * c - x2 * sn);
    dp[d + 32] = f2h_bits(x2 * c + x1 * sn);
}

// ---------------------------------------------------------------------------
// MFMA flash attention (fp16 inputs, fp32 accumulate).
// Block = (qtile 64, head). 4 waves x 16 q-rows. 32KB LDS, XOR swizzle.
__global__ __launch_bounds__(256)
void k_attn_mfma(const u16* __restrict__ qb, const u16* __restrict__ kb,
                 const u16* __restrict__ vb, u16* __restrict__ ob) {
    __shared__ u16 Qs[64 * 64];
    __shared__ u16 Ks[64 * 64];
    __shared__ u16 Vt[64 * 64];
    __shared__ u16 Ps[64 * 64];
    const int qt = blockIdx.x, h = blockIdx.y, kvh = h >> 2;
    const int tid = threadIdx.x, lane = tid & 63, w = tid >> 6;
    const int ln = lane & 15, quad = lane >> 4;

#pragma unroll
    for (int p = 0; p < 2; p++) {
        int r = p * 32 + (tid >> 3), c = tid & 7;
        uint4 v = *(const uint4*)(qb + (size_t)(qt * 64 + r) * (NHEAD * HD) +
                                  h * HD + c * 8);
        *(uint4*)&Qs[r * 64 + ((c ^ (r & 7)) << 3)] = v;
    }

    float m_[4], l_[4];
    f32x4 Oa[4];
#pragma unroll
    for (int r = 0; r < 4; r++) { m_[r] = NEG_INF; l_[r] = 0.0f; }
#pragma unroll
    for (int nt = 0; nt < 4; nt++) Oa[nt] = (f32x4){0.f, 0.f, 0.f, 0.f};

    for (int kt = 0; kt <= qt; kt++) {
        __syncthreads();
#pragma unroll
        for (int p = 0; p < 2; p++) {
            int r = p * 32 + (tid >> 3), c = tid & 7;
            uint4 v = *(const uint4*)(kb + (size_t)(kt * 64 + r) * (NKVH * HD) +
                                      kvh * HD + c * 8);
            *(uint4*)&Ks[r * 64 + ((c ^ (r & 7)) << 3)] = v;
        }
        {
            int s = tid & 63;
#pragma unroll
            for (int half = 0; half < 2; half++) {
                int d0 = w * 16 + half * 8;
                uint4 v = *(const uint4*)(vb + (size_t)(kt * 64 + s) * (NKVH * HD) +
                                          kvh * HD + d0);
                u16 a[8];
                a[0] = (u16)(v.x & 0xffff); a[1] = (u16)(v.x >> 16);
                a[2] = (u16)(v.y & 0xffff); a[3] = (u16)(v.y >> 16);
                a[4] = (u16)(v.z & 0xffff); a[5] = (u16)(v.z >> 16);
                a[6] = (u16)(v.w & 0xffff); a[7] = (u16)(v.w >> 16);
#pragma unroll
                for (int j = 0; j < 8; j++) {
                    int d = d0 + j;
                    Vt[d * 64 + (((s >> 3) ^ (d & 7)) << 3) + (s & 7)] = a[j];
                }
            }
        }
        __syncthreads();

        // S = Q K^T
        f32x4 sc[4];
#pragma unroll
        for (int nt = 0; nt < 4; nt++) sc[nt] = (f32x4){0.f, 0.f, 0.f, 0.f};
#pragma unroll
        for (int ks = 0; ks < 2; ks++) {
            int arow = 16 * w + ln;
            f16x8 af = *(const f16x8*)&Qs[arow * 64 +
                                          (((ks * 4 + quad) ^ (arow & 7)) << 3)];
#pragma unroll
            for (int nt = 0; nt < 4; nt++) {
                int brow = nt * 16 + ln;
                f16x8 bf = *(const f16x8*)&Ks[brow * 64 +
                                              (((ks * 4 + quad) ^ (brow & 7)) << 3)];
                sc[nt] = __builtin_amdgcn_mfma_f32_16x16x32_f16(af, bf, sc[nt],
                                                                0, 0, 0);
            }
        }

        const bool diag = (kt == qt);
        float mt[4];
#pragma unroll
        for (int r = 0; r < 4; r++) {
            int qrow = quad * 4 + r + 16 * w;
#pragma unroll
            for (int nt = 0; nt < 4; nt++) {
                float s = sc[nt][r] * 0.125f;
                if (diag && (nt * 16 + ln) > qrow) s = NEG_INF;
                sc[nt][r] = s;
            }
            mt[r] = fmaxf(fmaxf(sc[0][r], sc[1][r]), fmaxf(sc[2][r], sc[3][r]));
        }
#pragma unroll
        for (int off = 8; off >= 1; off >>= 1)
#pragma unroll
            for (int r = 0; r < 4; r++)
                mt[r] = fmaxf(mt[r], __shfl_xor(mt[r], off, 64));

        float rs[4];
#pragma unroll
        for (int r = 0; r < 4; r++) {
            float mn = fmaxf(m_[r], mt[r]);
            float al = exp2f((m_[r] - mn) * LOG2E);
            m_[r] = mn;
            float acc0 = 0.0f;
#pragma unroll
            for (int nt = 0; nt < 4; nt++) {
                float pv = exp2f((sc[nt][r] - mn) * LOG2E);
                sc[nt][r] = pv;
                acc0 += pv;
            }
            rs[r] = acc0;
            l_[r] *= al;
#pragma unroll
            for (int nt = 0; nt < 4; nt++) Oa[nt][r] *= al;
        }
#pragma unroll
        for (int off = 8; off >= 1; off >>= 1)
#pragma unroll
            for (int r = 0; r < 4; r++) rs[r] += __shfl_xor(rs[r], off, 64);
#pragma unroll
        for (int r = 0; r < 4; r++) l_[r] += rs[r];

#pragma unroll
        for (int r = 0; r < 4; r++) {
            int row = 16 * w + quad * 4 + r;
#pragma unroll
            for (int nt = 0; nt < 4; nt++) {
                int ch = nt * 2 + (ln >> 3);
                Ps[row * 64 + ((ch ^ (row & 7)) << 3) + (ln & 7)] =
                    f2h_bits(sc[nt][r]);
            }
        }
        __syncthreads();

        // O += P V
#pragma unroll
        for (int ks = 0; ks < 2; ks++) {
            int arow = 16 * w + ln;
            f16x8 pf = *(const f16x8*)&Ps[arow * 64 +
                                          (((ks * 4 + quad) ^ (arow & 7)) << 3)];
#pragma unroll
            for (int nt = 0; nt < 4; nt++) {
                int vrow = nt * 16 + ln;
                f16x8 vf = *(const f16x8*)&Vt[vrow * 64 +
                                              (((ks * 4 + quad) ^ (vrow & 7)) << 3)];
                Oa[nt] = __builtin_amdgcn_mfma_f32_16x16x32_f16(pf, vf, Oa[nt],
                                                                0, 0, 0);
            }
        }
    }

#pragma unroll
    for (int r = 0; r < 4; r++) {
        float inv = 1.0f / l_[r];
        int sg = qt * 64 + 16 * w + quad * 4 + r;
#pragma unroll
        for (int nt = 0; nt < 4; nt++) {
            int d = nt * 16 + ln;
            ob[(size_t)sg * HDIM + h * HD + d] = f2bf(Oa[nt][r] * inv);
        }
    }
}

// ---------------------------------------------------------------------------
__global__ __launch_bounds__(64)
void k_gate(const float* __restrict__ Hst, const float* __restrict__ PW,
            const float* __restrict__ GW, int* __restrict__ cnt,
            int* __restrict__ top_i, float* __restrict__ top_w) {
    int t = blockIdx.x;
    int lane = threadIdx.x;
    const float* hrow = Hst + (size_t)t * HDIM;
    float ss = 0.0f;
    float acc[NEXP] = {};
    for (int hh = lane; hh < HDIM; hh += 64) {
        float hv = hrow[hh];
        ss += hv * hv;
        float xw = hv * PW[hh];
        const float* g = GW + (size_t)hh * NEXP;
#pragma unroll
        for (int e = 0; e < NEXP; e++) acc[e] += xw * g[e];
    }
#pragma unroll
    for (int off = 32; off >= 1; off >>= 1) {
        ss += __shfl_xor(ss, off, 64);
#pragma unroll
        for (int e = 0; e < NEXP; e++) acc[e] += __shfl_xor(acc[e], off, 64);
    }
    if (lane == 0) {
        float rstd = rsqrtf(ss * (1.0f / HDIM) + EPS_F);
        int e0 = 0;
        for (int e = 1; e < NEXP; e++) if (acc[e] > acc[e0]) e0 = e;
        int e1 = (e0 == 0) ? 1 : 0;
        for (int e = 0; e < NEXP; e++)
            if (e != e0 && acc[e] > acc[e1]) e1 = e;
        float w0 = 1.0f / (1.0f + expf((acc[e1] - acc[e0]) * rstd));
        top_i[t * 2 + 0] = e0; top_i[t * 2 + 1] = e1;
        top_w[t * 2 + 0] = w0; top_w[t * 2 + 1] = 1.0f - w0;
        atomicAdd(&cnt[e0], 1);
        atomicAdd(&cnt[e1], 1);
    }
}

__global__ void k_prefix(const int* __restrict__ cnt, int* __restrict__ offs,
                         int* __restrict__ cur) {
    if (blockIdx.x == 0 && threadIdx.x == 0) {
        int a = 0;
        for (int e = 0; e < NEXP; e++) { offs[e] = a; cur[e] = a; a += cnt[e]; }
        offs[NEXP] = a;
    }
}

__global__ __launch_bounds__(256)
void k_fill(const int* __restrict__ top_i, int* __restrict__ cur,
            int* __restrict__ idxg, int* __restrict__ slot) {
    int t = blockIdx.x * blockDim.x + threadIdx.x;
    if (t >= S_LEN) return;
#pragma unroll
    for (int kk = 0; kk < 2; kk++) {
        int e = top_i[t * 2 + kk];
        int p = atomicAdd(&cur[e], 1);
        idxg[p] = t;
        slot[t * 2 + kk] = p;
    }
}

__global__ __launch_bounds__(256)
void k_gather(const u16* __restrict__ xnb, const int* __restrict__ idxg,
              u16* __restrict__ Xg) {
    int p = blockIdx.x;
    int t = idxg[p];
    const uint2* s = (const uint2*)(xnb + (size_t)t * HDIM);
    uint2* d = (uint2*)(Xg + (size_t)p * HDIM);
    d[threadIdx.x] = s[threadIdx.x];
}

__global__ __launch_bounds__(256)
void k_combine(const float* __restrict__ oexp, const int* __restrict__ slot,
               const float* __restrict__ top_w, float* __restrict__ out) {
    int t = blockIdx.x, tid = threadIdx.x;
    int s0 = slot[t * 2], s1 = slot[t * 2 + 1];
    float w0 = top_w[t * 2], w1 = top_w[t * 2 + 1];
    float4 a = ((const float4*)(oexp + (size_t)s0 * HDIM))[tid];
    float4 b = ((const float4*)(oexp + (size_t)s1 * HDIM))[tid];
    float4* o = (float4*)(out + (size_t)t * HDIM);
    float4 c = o[tid];
    c.x += w0 * a.x + w1 * b.x;
    c.y += w0 * a.y + w1 * b.y;
    c.z += w0 * a.z + w1 * b.z;
    c.w += w0 * a.w + w1 * b.w;
    o[tid] = c;
}

// ===========================================================================
extern "C" void kernel_launch(void* const* d_in, const int* in_sizes, int n_in,
                              void* d_out, int out_size, void* d_ws,
                              size_t ws_size, hipStream_t stream) {
    (void)in_sizes; (void)n_in; (void)out_size; (void)ws_size;
    const float* hidden = (const float*)d_in[0];
    const int*   pos    = (const int*)d_in[1];
    const float* wq     = (const float*)d_in[2];
    const float* wk     = (const float*)d_in[3];
    const float* wv     = (const float*)d_in[4];
    const float* wo     = (const float*)d_in[5];
    const float* innw   = (const float*)d_in[6];
    const float* postnw = (const float*)d_in[7];
    const float* gatew  = (const float*)d_in[8];
    const float* w1     = (const float*)d_in[9];
    const float* w3     = (const float*)d_in[10];
    const float* w2     = (const float*)d_in[11];
    float* out = (float*)d_out;

    // ---- workspace layout ----
    u16* w1t  = (u16*)d_ws;
    u16* w3t  = w1t + (size_t)NEXP * ISZ * HDIM;
    u16* w2t  = w3t + (size_t)NEXP * ISZ * HDIM;
    u16* qkvt = w2t + (size_t)NEXP * ISZ * HDIM;
    u16* wot  = qkvt + (size_t)1536 * HDIM;
    u16* xnb  = wot + (size_t)HDIM * HDIM;
    float* qbuf = (float*)(xnb + (size_t)S_LEN * HDIM);          // 2M fp32
    float* kbuf = qbuf + (size_t)S_LEN * HDIM;                   // 0.5M fp32
    u16* vb16   = (u16*)(kbuf + (size_t)S_LEN * NKVH * HD);      // 0.5M u16 (fp16)
    u16* qb2    = vb16 + (size_t)S_LEN * NKVH * HD;              // 2M u16 (fp16)
    u16* kb2    = qb2 + (size_t)S_LEN * HDIM;                    // 0.5M u16 (fp16)
    u16* attnb  = kb2 + (size_t)S_LEN * NKVH * HD;               // 2M u16 (bf16)
    float* oexp = qbuf;   // overlay: q/k/v/qb2/kb2 dead before oexp written
    u16* Xg  = attnb + (size_t)S_LEN * HDIM;
    u16* hg3 = Xg + (size_t)NSLOT * HDIM;
    u16* he  = hg3 + (size_t)NSLOT * ISZ;
    int* ib  = (int*)(he + (size_t)NSLOT * ISZ);
    int*   cnt   = ib;
    int*   offs  = ib + 16;
    int*   cur   = ib + 32;
    int*   top_i = ib + 64;
    int*   slot  = ib + 64 + 4096;
    int*   idxg  = ib + 64 + 8192;
    float* top_w = (float*)(ib + 64 + 12288);

    const long long HI = (long long)HDIM * ISZ;

    k_zero_ints<<<1, 64, 0, stream>>>(cnt, 64);
    k_rmsnorm_bf<<<S_LEN, 256, 0, stream>>>(hidden, innw, xnb);

    // weight transpose+convert (dst [N][K] bf16)
    k_cvt_t<<<dim3(16, 8, 1), 256, 0, stream>>>(wq, qkvt, 1024, 1024, 0, 0);
    k_cvt_t<<<dim3(4, 8, 1), 256, 0, stream>>>(wk, qkvt + (size_t)1024 * 1024, 1024, 256, 0, 0);
    k_cvt_t<<<dim3(4, 8, 1), 256, 0, stream>>>(wv, qkvt + (size_t)1280 * 1024, 1024, 256, 0, 0);
    k_cvt_t<<<dim3(16, 8, 1), 256, 0, stream>>>(wo, wot, 1024, 1024, 0, 0);
    k_cvt_t<<<dim3(56, 8, NEXP), 256, 0, stream>>>(w1, w1t, 1024, 3584, HI, HI);
    k_cvt_t<<<dim3(56, 8, NEXP), 256, 0, stream>>>(w3, w3t, 1024, 3584, HI, HI);
    k_cvt_t<<<dim3(16, 28, NEXP), 256, 0, stream>>>(w2, w2t, 3584, 1024, HI, HI);

    // qkv projection: q,k fp32 + v fp16
    k_gemm_bt<<<dim3(12, 16), 256, 0, stream>>>(xnb, qkvt, 2048, 1536, 1024, 3,
                                                qbuf, kbuf, nullptr, vb16);
    k_rope_cvt<<<(S_LEN * (NHEAD + NKVH) * 32) / 256, 256, 0, stream>>>(
        qbuf, kbuf, pos, qb2, kb2);
    k_attn_mfma<<<dim3(32, 16), 256, 0, stream>>>(qb2, kb2, vb16, attnb);
    // wo + residual -> d_out (h)
    k_gemm_bt<<<dim3(8, 16), 256, 0, stream>>>(attnb, wot, 2048, 1024, 1024, 2,
                                               out, nullptr, hidden, nullptr);
    // post-norm -> xnb ; gate from fp32 h (norm fused)
    k_rmsnorm_bf<<<S_LEN, 256, 0, stream>>>(out, postnw, xnb);
    k_gate<<<S_LEN, 64, 0, stream>>>(out, postnw, gatew, cnt, top_i, top_w);
    k_prefix<<<1, 1, 0, stream>>>(cnt, offs, cur);
    k_fill<<<S_LEN / 256, 256, 0, stream>>>(top_i, cur, idxg, slot);
    k_gather<<<NSLOT, 256, 0, stream>>>(xnb, idxg, Xg);

    // MoE grouped GEMMs
    k_gemm_bt_moe<<<dim3(28, 16, NEXP), 256, 0, stream>>>(Xg, w3t, 3584, 1024, 1,
                                                          nullptr, hg3, nullptr, offs);
    k_gemm_bt_moe<<<dim3(28, 16, NEXP), 256, 0, stream>>>(Xg, w1t, 3584, 1024, 2,
                                                          nullptr, he, hg3, offs);
    k_gemm_bt_moe<<<dim3(8, 16, NEXP), 256, 0, stream>>>(he, w2t, 1024, 3584, 0,
                                                         oexp, nullptr, nullptr, offs);
    k_combine<<<S_LEN, 256, 0, stream>>>(oexp, slot, top_w, out);
}

// Round 5
// 924.537 us; speedup vs baseline: 2.8857x; 1.0822x over previous
//
#include <hip/hip_runtime.h>
#include <math.h>

// ============================================================================
// MixtralDecoderLayer on MI355X — Round 4: double-buffered GEMM K-loops.
//
// Change vs round 3: all MFMA GEMMs use a 2-stage LDS pipeline (prefetch tile
// k+1 after the barrier, compute tile k) -> the barrier's vmcnt(0) drain waits
// on a load issued one compute-phase earlier. One barrier/iter instead of two.
// w2 MoE GEMM additionally split-K=2 (partials to oexpA/oexpB, summed in
// combine) to double its working-block count.
// ============================================================================

typedef unsigned short u16;
typedef unsigned int u32;
typedef __attribute__((ext_vector_type(8))) short s16x8;
typedef __attribute__((ext_vector_type(8))) _Float16 f16x8;
typedef __attribute__((ext_vector_type(4))) float f32x4;

#define S_LEN 2048
#define HDIM  1024
#define NHEAD 16
#define NKVH  4
#define HD    64
#define ISZ   3584
#define NEXP  8
#define NSLOT 4096
#define EPS_F 1e-5f
#define NEG_INF -1e30f
#define LOG2E 1.44269504f

__device__ __forceinline__ float bf2f(u16 u) {
    union { u32 i; float f; } c; c.i = ((u32)u) << 16; return c.f;
}
__device__ __forceinline__ u16 f2bf(float f) {
    union { float f; u32 i; } c; c.f = f;
    u32 r = (c.i + 0x7fffu + ((c.i >> 16) & 1u)) >> 16;
    return (u16)r;
}
__device__ __forceinline__ u16 f2h_bits(float f) {
    union { _Float16 h; u16 u; } c; c.h = (_Float16)f; return c.u;
}
__device__ __forceinline__ void async16(const u16* g, u16* l) {
    __builtin_amdgcn_global_load_lds(
        (const __attribute__((address_space(1))) void*)g,
        (__attribute__((address_space(3))) void*)l, 16, 0, 0);
}

// ---------------------------------------------------------------------------
__global__ void k_zero_ints(int* __restrict__ p, int n) {
    int i = blockIdx.x * blockDim.x + threadIdx.x;
    if (i < n) p[i] = 0;
}

// ---------------------------------------------------------------------------
__global__ __launch_bounds__(256)
void k_rmsnorm_bf(const float* __restrict__ x, const float* __restrict__ w,
                  u16* __restrict__ out) {
    int t = blockIdx.x;
    int tid = threadIdx.x;
    float4 v = ((const float4*)(x + (size_t)t * HDIM))[tid];
    float ss = v.x * v.x + v.y * v.y + v.z * v.z + v.w * v.w;
#pragma unroll
    for (int off = 32; off >= 1; off >>= 1) ss += __shfl_xor(ss, off, 64);
    __shared__ float red[4];
    if ((tid & 63) == 0) red[tid >> 6] = ss;
    __syncthreads();
    float tot = red[0] + red[1] + red[2] + red[3];
    float rstd = rsqrtf(tot * (1.0f / HDIM) + EPS_F);
    float4 wv = ((const float4*)w)[tid];
    uint2 pk;
    pk.x = (u32)f2bf(v.x * rstd * wv.x) | ((u32)f2bf(v.y * rstd * wv.y) << 16);
    pk.y = (u32)f2bf(v.z * rstd * wv.z) | ((u32)f2bf(v.w * rstd * wv.w) << 16);
    ((uint2*)(out + (size_t)t * HDIM))[tid] = pk;
}

// ---------------------------------------------------------------------------
// Transpose + convert: src fp32 [R][C] -> dst bf16 [C][R].
__global__ __launch_bounds__(256)
void k_cvt_t(const float* __restrict__ src, u16* __restrict__ dst,
             int R, int C, long long srcZ, long long dstZ) {
    const int z = blockIdx.z;
    src += (size_t)z * srcZ;
    dst += (size_t)z * dstZ;
    const int lane = threadIdx.x & 63, w = threadIdx.x >> 6;
    const int c = blockIdx.x * 64 + lane;
    const int r0 = blockIdx.y * 128 + w * 32;
    float v[32];
#pragma unroll
    for (int i = 0; i < 32; i++) v[i] = src[(size_t)(r0 + i) * C + c];
#pragma unroll
    for (int g = 0; g < 4; g++) {
        uint4 pk;
        pk.x = (u32)f2bf(v[g * 8 + 0]) | ((u32)f2bf(v[g * 8 + 1]) << 16);
        pk.y = (u32)f2bf(v[g * 8 + 2]) | ((u32)f2bf(v[g * 8 + 3]) << 16);
        pk.z = (u32)f2bf(v[g * 8 + 4]) | ((u32)f2bf(v[g * 8 + 5]) << 16);
        pk.w = (u32)f2bf(v[g * 8 + 6]) | ((u32)f2bf(v[g * 8 + 7]) << 16);
        *(uint4*)(&dst[(size_t)c * R + r0 + g * 8]) = pk;
    }
}

// ---------------------------------------------------------------------------
// Stage one 128x32 A-tile + 128x32 B-tile (bf16) into `buf` via async16.
__device__ __forceinline__ void stage32(const u16* __restrict__ A,
                                        const u16* __restrict__ Bt, int K,
                                        int rowA0, int rowAmax, int n0, int kc,
                                        u16* buf, int wid, int sr, int sc) {
#pragma unroll
    for (int t = 0; t < 2; t++) {
        int row = wid * 32 + t * 16 + sr;
        int ck = (sc ^ (row & 3)) << 3;
        int ra = rowA0 + row;
        if (ra > rowAmax) ra = rowAmax;
        u16* ldsA = buf + (wid * 32 + t * 16) * 32;
        async16(A + (size_t)ra * K + kc + ck, ldsA);
        async16(Bt + (size_t)(n0 + row) * K + kc + ck, ldsA + 4096);
    }
}

// ---------------------------------------------------------------------------
// Double-buffered MFMA GEMM core: C[128,128] += A[rows,kbeg:kend] @ Bt^T.
// lds must be 16384 u16 (32 KB): two 8192-elem buffers (A @0, B @4096 each).
__device__ __forceinline__ void gemm128_dbuf(
    const u16* __restrict__ A, const u16* __restrict__ Bt, int K,
    int kbeg, int kend, int rowA0, int rowAmax, int n0,
    u16* lds, f32x4 acc[4][4]) {
    const int tid = threadIdx.x;
    const int lane = tid & 63, wid = tid >> 6;
    const int sr = lane >> 2, sc = lane & 3;
    const int ln = lane & 15, q = lane >> 4;
    const int wm = wid >> 1, wn = wid & 1;
    stage32(A, Bt, K, rowA0, rowAmax, n0, kbeg, lds, wid, sr, sc);
    int pp = 0;
    for (int kc = kbeg; kc < kend; kc += 32) {
        u16* cur = lds + pp * 8192;
        u16* nxt = lds + (pp ^ 1) * 8192;
        pp ^= 1;
        __syncthreads();   // drains vmcnt -> stage(kc) done; stage was issued
                           // one compute-phase ago, so latency is overlapped
        if (kc + 32 < kend)
            stage32(A, Bt, K, rowA0, rowAmax, n0, kc + 32, nxt, wid, sr, sc);
        s16x8 af[4], bfv[4];
#pragma unroll
        for (int i = 0; i < 4; i++) {
            int ar = wm * 64 + i * 16 + ln;
            af[i] = *(const s16x8*)(cur + ar * 32 + ((q ^ (ar & 3)) << 3));
            int br = wn * 64 + i * 16 + ln;
            bfv[i] = *(const s16x8*)(cur + 4096 + br * 32 + ((q ^ (br & 3)) << 3));
        }
#pragma unroll
        for (int i = 0; i < 4; i++)
#pragma unroll
            for (int j = 0; j < 4; j++)
                acc[i][j] = __builtin_amdgcn_mfma_f32_16x16x32_bf16(
                    af[i], bfv[j], acc[i][j], 0, 0, 0);
    }
}

// ---------------------------------------------------------------------------
// Flat GEMM.  mode 0: fp32->F0 | 1: bf16->O16 | 2: fp32+RES->F0 |
//             3: qkv split -> F0(q fp32) F1(k fp32) O16(v fp16 bits)
__global__ __launch_bounds__(256, 2)
void k_gemm_bt(const u16* __restrict__ A, const u16* __restrict__ Bt,
               int M, int N, int K, int mode,
               float* __restrict__ F0, float* __restrict__ F1,
               const float* __restrict__ RES, u16* __restrict__ O16) {
    __shared__ u16 lds[16384];
    const int m0 = blockIdx.y * 128, n0 = blockIdx.x * 128;
    f32x4 acc[4][4];
#pragma unroll
    for (int i = 0; i < 4; i++)
#pragma unroll
        for (int j = 0; j < 4; j++) acc[i][j] = (f32x4){0.f, 0.f, 0.f, 0.f};
    gemm128_dbuf(A, Bt, K, 0, K, m0, M - 1, n0, lds, acc);
    const int lane = threadIdx.x & 63, wid = threadIdx.x >> 6;
    const int ln = lane & 15, q = lane >> 4, wm = wid >> 1, wn = wid & 1;
#pragma unroll
    for (int i = 0; i < 4; i++) {
#pragma unroll
        for (int r = 0; r < 4; r++) {
            int m = m0 + wm * 64 + i * 16 + q * 4 + r;
#pragma unroll
            for (int j = 0; j < 4; j++) {
                int n = n0 + wn * 64 + j * 16 + ln;
                float v = acc[i][j][r];
                if (mode == 0) {
                    F0[(size_t)m * N + n] = v;
                } else if (mode == 1) {
                    O16[(size_t)m * N + n] = f2bf(v);
                } else if (mode == 2) {
                    F0[(size_t)m * N + n] = v + RES[(size_t)m * N + n];
                } else {
                    if (n < 1024)       F0[(size_t)m * 1024 + n] = v;
                    else if (n < 1280)  F1[(size_t)m * 256 + (n - 1024)] = v;
                    else                O16[(size_t)m * 256 + (n - 1280)] = f2h_bits(v);
                }
            }
        }
    }
}

// ---------------------------------------------------------------------------
// Grouped MoE GEMM (w1/w3).  mode 1: bf16->O16 | 2: silu(acc)*AUX->O16
__global__ __launch_bounds__(256, 2)
void k_gemm_bt_moe(const u16* __restrict__ A, const u16* __restrict__ WT,
                   int N, int K, int mode,
                   u16* __restrict__ O16, const u16* __restrict__ AUX,
                   const int* __restrict__ offs) {
    const int e = blockIdx.z;
    const int base = offs[e], cnt = offs[e + 1] - base;
    const int m0 = blockIdx.y * 128;
    if (m0 >= cnt) return;
    __shared__ u16 lds[16384];
    const u16* Bt = WT + (size_t)e * N * K;
    const int n0 = blockIdx.x * 128;
    f32x4 acc[4][4];
#pragma unroll
    for (int i = 0; i < 4; i++)
#pragma unroll
        for (int j = 0; j < 4; j++) acc[i][j] = (f32x4){0.f, 0.f, 0.f, 0.f};
    gemm128_dbuf(A, Bt, K, 0, K, base + m0, NSLOT - 1, n0, lds, acc);
    const int lane = threadIdx.x & 63, wid = threadIdx.x >> 6;
    const int ln = lane & 15, q = lane >> 4, wm = wid >> 1, wn = wid & 1;
#pragma unroll
    for (int i = 0; i < 4; i++) {
#pragma unroll
        for (int r = 0; r < 4; r++) {
            int mloc = wm * 64 + i * 16 + q * 4 + r;
            if (m0 + mloc >= cnt) continue;
            size_t row = (size_t)(base + m0 + mloc);
#pragma unroll
            for (int j = 0; j < 4; j++) {
                int n = n0 + wn * 64 + j * 16 + ln;
                float v = acc[i][j][r];
                if (mode == 1) {
                    O16[row * N + n] = f2bf(v);
                } else {
                    float a = bf2f(AUX[row * N + n]);
                    float s = v / (1.0f + expf(-v));
                    O16[row * N + n] = f2bf(s * a);
                }
            }
        }
    }
}

// ---------------------------------------------------------------------------
// MoE w2 GEMM, split-K=2: z = e + 8*half; half 0 -> OA, half 1 -> OB (fp32).
__global__ __launch_bounds__(256, 2)
void k_moe_w2(const u16* __restrict__ He, const u16* __restrict__ W2T,
              float* __restrict__ OA, float* __restrict__ OB,
              const int* __restrict__ offs) {
    const int z = blockIdx.z;
    const int e = z & 7, half = z >> 3;
    const int base = offs[e], cnt = offs[e + 1] - base;
    const int m0 = blockIdx.y * 128;
    if (m0 >= cnt) return;
    __shared__ u16 lds[16384];
    const u16* Bt = W2T + (size_t)e * HDIM * ISZ;
    const int n0 = blockIdx.x * 128;
    f32x4 acc[4][4];
#pragma unroll
    for (int i = 0; i < 4; i++)
#pragma unroll
        for (int j = 0; j < 4; j++) acc[i][j] = (f32x4){0.f, 0.f, 0.f, 0.f};
    gemm128_dbuf(He, Bt, ISZ, half * (ISZ / 2), (half + 1) * (ISZ / 2),
                 base + m0, NSLOT - 1, n0, lds, acc);
    float* F0 = half ? OB : OA;
    const int lane = threadIdx.x & 63, wid = threadIdx.x >> 6;
    const int ln = lane & 15, q = lane >> 4, wm = wid >> 1, wn = wid & 1;
#pragma unroll
    for (int i = 0; i < 4; i++) {
#pragma unroll
        for (int r = 0; r < 4; r++) {
            int mloc = wm * 64 + i * 16 + q * 4 + r;
            if (m0 + mloc >= cnt) continue;
            size_t row = (size_t)(base + m0 + mloc);
#pragma unroll
            for (int j = 0; j < 4; j++) {
                int n = n0 + wn * 64 + j * 16 + ln;
                F0[row * HDIM + n] = acc[i][j][r];
            }
        }
    }
}

// ---------------------------------------------------------------------------
// RoPE + convert to fp16 bits.
__global__ __launch_bounds__(256)
void k_rope_cvt(const float* __restrict__ q, const float* __restrict__ k,
                const int* __restrict__ pos, u16* __restrict__ qb2,
                u16* __restrict__ kb2) {
    int id = blockIdx.x * blockDim.x + threadIdx.x;
    int d = id & 31;
    int hh = (id >> 5) % (NHEAD + NKVH);
    int s = id / ((NHEAD + NKVH) * 32);
    float p = (float)pos[s];
    float inv = exp2f(-((float)(2 * d) / (float)HD) * log2f(1.0e6f));
    float ang = p * inv;
    float c = cosf(ang), sn = sinf(ang);
    const float* sp; u16* dp;
    if (hh < NHEAD) {
        sp = q + (size_t)s * (NHEAD * HD) + hh * HD;
        dp = qb2 + (size_t)s * (NHEAD * HD) + hh * HD;
    } else {
        sp = k + (size_t)s * (NKVH * HD) + (hh - NHEAD) * HD;
        dp = kb2 + (size_t)s * (NKVH * HD) + (hh - NHEAD) * HD;
    }
    float x1 = sp[d], x2 = sp[d + 32];
    dp[d]      = f2h_bits(x1 * c - x2 * sn);
    dp[d + 32] = f2h_bits(x2 * c + x1 * sn);
}

// ---------------------------------------------------------------------------
// MFMA flash attention (fp16 inputs, fp32 accumulate). Round-3-verified.
__global__ __launch_bounds__(256)
void k_attn_mfma(const u16* __restrict__ qb, const u16* __restrict__ kb,
                 const u16* __restrict__ vb, u16* __restrict__ ob) {
    __shared__ u16 Qs[64 * 64];
    __shared__ u16 Ks[64 * 64];
    __shared__ u16 Vt[64 * 64];
    __shared__ u16 Ps[64 * 64];
    const int qt = blockIdx.x, h = blockIdx.y, kvh = h >> 2;
    const int tid = threadIdx.x, lane = tid & 63, w = tid >> 6;
    const int ln = lane & 15, quad = lane >> 4;

#pragma unroll
    for (int p = 0; p < 2; p++) {
        int r = p * 32 + (tid >> 3), c = tid & 7;
        uint4 v = *(const uint4*)(qb + (size_t)(qt * 64 + r) * (NHEAD * HD) +
                                  h * HD + c * 8);
        *(uint4*)&Qs[r * 64 + ((c ^ (r & 7)) << 3)] = v;
    }

    float m_[4], l_[4];
    f32x4 Oa[4];
#pragma unroll
    for (int r = 0; r < 4; r++) { m_[r] = NEG_INF; l_[r] = 0.0f; }
#pragma unroll
    for (int nt = 0; nt < 4; nt++) Oa[nt] = (f32x4){0.f, 0.f, 0.f, 0.f};

    for (int kt = 0; kt <= qt; kt++) {
        __syncthreads();
#pragma unroll
        for (int p = 0; p < 2; p++) {
            int r = p * 32 + (tid >> 3), c = tid & 7;
            uint4 v = *(const uint4*)(kb + (size_t)(kt * 64 + r) * (NKVH * HD) +
                                      kvh * HD + c * 8);
            *(uint4*)&Ks[r * 64 + ((c ^ (r & 7)) << 3)] = v;
        }
        {
            int s = tid & 63;
#pragma unroll
            for (int half = 0; half < 2; half++) {
                int d0 = w * 16 + half * 8;
                uint4 v = *(const uint4*)(vb + (size_t)(kt * 64 + s) * (NKVH * HD) +
                                          kvh * HD + d0);
                u16 a[8];
                a[0] = (u16)(v.x & 0xffff); a[1] = (u16)(v.x >> 16);
                a[2] = (u16)(v.y & 0xffff); a[3] = (u16)(v.y >> 16);
                a[4] = (u16)(v.z & 0xffff); a[5] = (u16)(v.z >> 16);
                a[6] = (u16)(v.w & 0xffff); a[7] = (u16)(v.w >> 16);
#pragma unroll
                for (int j = 0; j < 8; j++) {
                    int d = d0 + j;
                    Vt[d * 64 + (((s >> 3) ^ (d & 7)) << 3) + (s & 7)] = a[j];
                }
            }
        }
        __syncthreads();

        f32x4 sc[4];
#pragma unroll
        for (int nt = 0; nt < 4; nt++) sc[nt] = (f32x4){0.f, 0.f, 0.f, 0.f};
#pragma unroll
        for (int ks = 0; ks < 2; ks++) {
            int arow = 16 * w + ln;
            f16x8 af = *(const f16x8*)&Qs[arow * 64 +
                                          (((ks * 4 + quad) ^ (arow & 7)) << 3)];
#pragma unroll
            for (int nt = 0; nt < 4; nt++) {
                int brow = nt * 16 + ln;
                f16x8 bf = *(const f16x8*)&Ks[brow * 64 +
                                              (((ks * 4 + quad) ^ (brow & 7)) << 3)];
                sc[nt] = __builtin_amdgcn_mfma_f32_16x16x32_f16(af, bf, sc[nt],
                                                                0, 0, 0);
            }
        }

        const bool diag = (kt == qt);
        float mt[4];
#pragma unroll
        for (int r = 0; r < 4; r++) {
            int qrow = quad * 4 + r + 16 * w;
#pragma unroll
            for (int nt = 0; nt < 4; nt++) {
                float s = sc[nt][r] * 0.125f;
                if (diag && (nt * 16 + ln) > qrow) s = NEG_INF;
                sc[nt][r] = s;
            }
            mt[r] = fmaxf(fmaxf(sc[0][r], sc[1][r]), fmaxf(sc[2][r], sc[3][r]));
        }
#pragma unroll
        for (int off = 8; off >= 1; off >>= 1)
#pragma unroll
            for (int r = 0; r < 4; r++)
                mt[r] = fmaxf(mt[r], __shfl_xor(mt[r], off, 64));

        float rs[4];
#pragma unroll
        for (int r = 0; r < 4; r++) {
            float mn = fmaxf(m_[r], mt[r]);
            float al = exp2f((m_[r] - mn) * LOG2E);
            m_[r] = mn;
            float acc0 = 0.0f;
#pragma unroll
            for (int nt = 0; nt < 4; nt++) {
                float pv = exp2f((sc[nt][r] - mn) * LOG2E);
                sc[nt][r] = pv;
                acc0 += pv;
            }
            rs[r] = acc0;
            l_[r] *= al;
#pragma unroll
            for (int nt = 0; nt < 4; nt++) Oa[nt][r] *= al;
        }
#pragma unroll
        for (int off = 8; off >= 1; off >>= 1)
#pragma unroll
            for (int r = 0; r < 4; r++) rs[r] += __shfl_xor(rs[r], off, 64);
#pragma unroll
        for (int r = 0; r < 4; r++) l_[r] += rs[r];

#pragma unroll
        for (int r = 0; r < 4; r++) {
            int row = 16 * w + quad * 4 + r;
#pragma unroll
            for (int nt = 0; nt < 4; nt++) {
                int ch = nt * 2 + (ln >> 3);
                Ps[row * 64 + ((ch ^ (row & 7)) << 3) + (ln & 7)] =
                    f2h_bits(sc[nt][r]);
            }
        }
        __syncthreads();

#pragma unroll
        for (int ks = 0; ks < 2; ks++) {
            int arow = 16 * w + ln;
            f16x8 pf = *(const f16x8*)&Ps[arow * 64 +
                                          (((ks * 4 + quad) ^ (arow & 7)) << 3)];
#pragma unroll
            for (int nt = 0; nt < 4; nt++) {
                int vrow = nt * 16 + ln;
                f16x8 vf = *(const f16x8*)&Vt[vrow * 64 +
                                              (((ks * 4 + quad) ^ (vrow & 7)) << 3)];
                Oa[nt] = __builtin_amdgcn_mfma_f32_16x16x32_f16(pf, vf, Oa[nt],
                                                                0, 0, 0);
            }
        }
    }

#pragma unroll
    for (int r = 0; r < 4; r++) {
        float inv = 1.0f / l_[r];
        int sg = qt * 64 + 16 * w + quad * 4 + r;
#pragma unroll
        for (int nt = 0; nt < 4; nt++) {
            int d = nt * 16 + ln;
            ob[(size_t)sg * HDIM + h * HD + d] = f2bf(Oa[nt][r] * inv);
        }
    }
}

// ---------------------------------------------------------------------------
__global__ __launch_bounds__(64)
void k_gate(const float* __restrict__ Hst, const float* __restrict__ PW,
            const float* __restrict__ GW, int* __restrict__ cnt,
            int* __restrict__ top_i, float* __restrict__ top_w) {
    int t = blockIdx.x;
    int lane = threadIdx.x;
    const float* hrow = Hst + (size_t)t * HDIM;
    float ss = 0.0f;
    float acc[NEXP] = {};
    for (int hh = lane; hh < HDIM; hh += 64) {
        float hv = hrow[hh];
        ss += hv * hv;
        float xw = hv * PW[hh];
        const float* g = GW + (size_t)hh * NEXP;
#pragma unroll
        for (int e = 0; e < NEXP; e++) acc[e] += xw * g[e];
    }
#pragma unroll
    for (int off = 32; off >= 1; off >>= 1) {
        ss += __shfl_xor(ss, off, 64);
#pragma unroll
        for (int e = 0; e < NEXP; e++) acc[e] += __shfl_xor(acc[e], off, 64);
    }
    if (lane == 0) {
        float rstd = rsqrtf(ss * (1.0f / HDIM) + EPS_F);
        int e0 = 0;
        for (int e = 1; e < NEXP; e++) if (acc[e] > acc[e0]) e0 = e;
        int e1 = (e0 == 0) ? 1 : 0;
        for (int e = 0; e < NEXP; e++)
            if (e != e0 && acc[e] > acc[e1]) e1 = e;
        float w0 = 1.0f / (1.0f + expf((acc[e1] - acc[e0]) * rstd));
        top_i[t * 2 + 0] = e0; top_i[t * 2 + 1] = e1;
        top_w[t * 2 + 0] = w0; top_w[t * 2 + 1] = 1.0f - w0;
        atomicAdd(&cnt[e0], 1);
        atomicAdd(&cnt[e1], 1);
    }
}

__global__ void k_prefix(const int* __restrict__ cnt, int* __restrict__ offs,
                         int* __restrict__ cur) {
    if (blockIdx.x == 0 && threadIdx.x == 0) {
        int a = 0;
        for (int e = 0; e < NEXP; e++) { offs[e] = a; cur[e] = a; a += cnt[e]; }
        offs[NEXP] = a;
    }
}

__global__ __launch_bounds__(256)
void k_fill(const int* __restrict__ top_i, int* __restrict__ cur,
            int* __restrict__ idxg, int* __restrict__ slot) {
    int t = blockIdx.x * blockDim.x + threadIdx.x;
    if (t >= S_LEN) return;
#pragma unroll
    for (int kk = 0; kk < 2; kk++) {
        int e = top_i[t * 2 + kk];
        int p = atomicAdd(&cur[e], 1);
        idxg[p] = t;
        slot[t * 2 + kk] = p;
    }
}

__global__ __launch_bounds__(256)
void k_gather(const u16* __restrict__ xnb, const int* __restrict__ idxg,
              u16* __restrict__ Xg) {
    int p = blockIdx.x;
    int t = idxg[p];
    const uint2* s = (const uint2*)(xnb + (size_t)t * HDIM);
    uint2* d = (uint2*)(Xg + (size_t)p * HDIM);
    d[threadIdx.x] = s[threadIdx.x];
}

__global__ __launch_bounds__(256)
void k_combine2(const float* __restrict__ OA, const float* __restrict__ OB,
                const int* __restrict__ slot, const float* __restrict__ top_w,
                float* __restrict__ out) {
    int t = blockIdx.x, tid = threadIdx.x;
    int s0 = slot[t * 2], s1 = slot[t * 2 + 1];
    float w0 = top_w[t * 2], w1 = top_w[t * 2 + 1];
    float4 a0 = ((const float4*)(OA + (size_t)s0 * HDIM))[tid];
    float4 b0 = ((const float4*)(OB + (size_t)s0 * HDIM))[tid];
    float4 a1 = ((const float4*)(OA + (size_t)s1 * HDIM))[tid];
    float4 b1 = ((const float4*)(OB + (size_t)s1 * HDIM))[tid];
    float4* o = (float4*)(out + (size_t)t * HDIM);
    float4 c = o[tid];
    c.x += w0 * (a0.x + b0.x) + w1 * (a1.x + b1.x);
    c.y += w0 * (a0.y + b0.y) + w1 * (a1.y + b1.y);
    c.z += w0 * (a0.z + b0.z) + w1 * (a1.z + b1.z);
    c.w += w0 * (a0.w + b0.w) + w1 * (a1.w + b1.w);
    o[tid] = c;
}

// ===========================================================================
extern "C" void kernel_launch(void* const* d_in, const int* in_sizes, int n_in,
                              void* d_out, int out_size, void* d_ws,
                              size_t ws_size, hipStream_t stream) {
    (void)in_sizes; (void)n_in; (void)out_size; (void)ws_size;
    const float* hidden = (const float*)d_in[0];
    const int*   pos    = (const int*)d_in[1];
    const float* wq     = (const float*)d_in[2];
    const float* wk     = (const float*)d_in[3];
    const float* wv     = (const float*)d_in[4];
    const float* wo     = (const float*)d_in[5];
    const float* innw   = (const float*)d_in[6];
    const float* postnw = (const float*)d_in[7];
    const float* gatew  = (const float*)d_in[8];
    const float* w1     = (const float*)d_in[9];
    const float* w3     = (const float*)d_in[10];
    const float* w2     = (const float*)d_in[11];
    float* out = (float*)d_out;

    // ---- workspace layout ----
    u16* w1t  = (u16*)d_ws;
    u16* w3t  = w1t + (size_t)NEXP * ISZ * HDIM;
    u16* w2t  = w3t + (size_t)NEXP * ISZ * HDIM;
    u16* qkvt = w2t + (size_t)NEXP * ISZ * HDIM;
    u16* wot  = qkvt + (size_t)1536 * HDIM;
    u16* xnb  = wot + (size_t)HDIM * HDIM;
    float* qbuf = (float*)(xnb + (size_t)S_LEN * HDIM);          // 2M fp32
    float* kbuf = qbuf + (size_t)S_LEN * HDIM;                   // 0.5M fp32
    u16* vb16   = (u16*)(kbuf + (size_t)S_LEN * NKVH * HD);      // 0.5M u16 (fp16)
    u16* qb2    = vb16 + (size_t)S_LEN * NKVH * HD;              // 2M u16 (fp16)
    u16* kb2    = qb2 + (size_t)S_LEN * HDIM;                    // 0.5M u16 (fp16)
    u16* attnb  = kb2 + (size_t)S_LEN * NKVH * HD;               // 2M u16 (bf16)
    float* oexpA = qbuf;  // overlay (16 MB): q/k/v/qb2/kb2 dead before w2
    u16* Xg  = attnb + (size_t)S_LEN * HDIM;
    u16* hg3 = Xg + (size_t)NSLOT * HDIM;
    u16* he  = hg3 + (size_t)NSLOT * ISZ;
    float* oexpB = (float*)(he + (size_t)NSLOT * ISZ);           // 16 MB
    int* ib  = (int*)(oexpB + (size_t)NSLOT * HDIM);
    int*   cnt   = ib;
    int*   offs  = ib + 16;
    int*   cur   = ib + 32;
    int*   top_i = ib + 64;
    int*   slot  = ib + 64 + 4096;
    int*   idxg  = ib + 64 + 8192;
    float* top_w = (float*)(ib + 64 + 12288);

    const long long HI = (long long)HDIM * ISZ;

    k_zero_ints<<<1, 64, 0, stream>>>(cnt, 64);
    k_rmsnorm_bf<<<S_LEN, 256, 0, stream>>>(hidden, innw, xnb);

    // weight transpose+convert (dst [N][K] bf16)
    k_cvt_t<<<dim3(16, 8, 1), 256, 0, stream>>>(wq, qkvt, 1024, 1024, 0, 0);
    k_cvt_t<<<dim3(4, 8, 1), 256, 0, stream>>>(wk, qkvt + (size_t)1024 * 1024, 1024, 256, 0, 0);
    k_cvt_t<<<dim3(4, 8, 1), 256, 0, stream>>>(wv, qkvt + (size_t)1280 * 1024, 1024, 256, 0, 0);
    k_cvt_t<<<dim3(16, 8, 1), 256, 0, stream>>>(wo, wot, 1024, 1024, 0, 0);
    k_cvt_t<<<dim3(56, 8, NEXP), 256, 0, stream>>>(w1, w1t, 1024, 3584, HI, HI);
    k_cvt_t<<<dim3(56, 8, NEXP), 256, 0, stream>>>(w3, w3t, 1024, 3584, HI, HI);
    k_cvt_t<<<dim3(16, 28, NEXP), 256, 0, stream>>>(w2, w2t, 3584, 1024, HI, HI);

    // qkv projection: q,k fp32 + v fp16
    k_gemm_bt<<<dim3(12, 16), 256, 0, stream>>>(xnb, qkvt, 2048, 1536, 1024, 3,
                                                qbuf, kbuf, nullptr, vb16);
    k_rope_cvt<<<(S_LEN * (NHEAD + NKVH) * 32) / 256, 256, 0, stream>>>(
        qbuf, kbuf, pos, qb2, kb2);
    k_attn_mfma<<<dim3(32, 16), 256, 0, stream>>>(qb2, kb2, vb16, attnb);
    // wo + residual -> d_out (h)
    k_gemm_bt<<<dim3(8, 16), 256, 0, stream>>>(attnb, wot, 2048, 1024, 1024, 2,
                                               out, nullptr, hidden, nullptr);
    // post-norm -> xnb ; gate from fp32 h (norm fused)
    k_rmsnorm_bf<<<S_LEN, 256, 0, stream>>>(out, postnw, xnb);
    k_gate<<<S_LEN, 64, 0, stream>>>(out, postnw, gatew, cnt, top_i, top_w);
    k_prefix<<<1, 1, 0, stream>>>(cnt, offs, cur);
    k_fill<<<S_LEN / 256, 256, 0, stream>>>(top_i, cur, idxg, slot);
    k_gather<<<NSLOT, 256, 0, stream>>>(xnb, idxg, Xg);

    // MoE grouped GEMMs
    k_gemm_bt_moe<<<dim3(28, 16, NEXP), 256, 0, stream>>>(Xg, w3t, 3584, 1024, 1,
                                                          hg3, nullptr, offs);
    k_gemm_bt_moe<<<dim3(28, 16, NEXP), 256, 0, stream>>>(Xg, w1t, 3584, 1024, 2,
                                                          he, hg3, offs);
    k_moe_w2<<<dim3(8, 16, 16), 256, 0, stream>>>(he, w2t, oexpA, oexpB, offs);
    k_combine2<<<S_LEN, 256, 0, stream>>>(oexpA, oexpB, slot, top_w, out);
}